// Round 34
// baseline (128.166 us; speedup 1.0000x reference)
//
#include <hip/hip_runtime.h>

// ---------------------------------------------------------------------------
// MultiHeadAttention forward, MI355X (gfx950).
// Weights-only fp32->bf16 convert; Q/K/V projections (128x128/BK=32 GEMM,
// grid 768 = 3 blocks/CU, A = fp32 fused-convert with T14 split, B = bf16
// weights via global_load_lds, dual-barrier counted-vmcnt dbuf pipeline,
// XCD-chunked); flash attention v4b + XCD-chunked grid; output projection.
// (Converged best: 127.2-127.7 us across 5 runs.)
// ---------------------------------------------------------------------------

#define D_MODEL 1024
#define NHEADS  16
#define DKH     64
#define SEQ     2048
#define BATCH   2
#define MTOT    (BATCH * SEQ)            // 4096 rows
#define XE      ((long)MTOT * D_MODEL)   // 4194304 elems
#define WE      ((long)D_MODEL * D_MODEL)
#define QSCALE  0.18033688011112042f     // 0.125 * log2(e): softmax in exp2 domain

typedef __attribute__((ext_vector_type(8))) short short8v;   // 8 x bf16 (4 VGPR)
typedef __attribute__((ext_vector_type(4))) short short4v;   // 4 x bf16
typedef __attribute__((ext_vector_type(4))) float f32x4;     // MFMA C/D frag

typedef __attribute__((address_space(1))) void as1_void;
typedef __attribute__((address_space(3))) void as3_void;

__device__ __forceinline__ void gload16(const void* g, void* l) {
    __builtin_amdgcn_global_load_lds((const as1_void*)g, (as3_void*)l, 16, 0, 0);
}

__device__ __forceinline__ unsigned short f2bf(float x) {
    unsigned int u = __float_as_uint(x);
    u += 0x7FFFu + ((u >> 16) & 1u);     // RNE
    return (unsigned short)(u >> 16);
}

// native v_exp_f32: computes 2^x (avoid __exp2f: glibc name collision)
__device__ __forceinline__ float fexp2(float x) {
    return __builtin_amdgcn_exp2f(x);
}

// hardware packed f32x2 -> bf16x2 (RNE; one VALU op for two converts)
__device__ __forceinline__ unsigned int cvt_pk_bf16(float lo, float hi) {
    unsigned int r;
    asm("v_cvt_pk_bf16_f32 %0, %1, %2" : "=v"(r) : "v"(lo), "v"(hi));
    return r;
}

// XOR swizzle for [rows][64 bf16] LDS tiles (128B rows).
__device__ __forceinline__ int swz_u(int row, int col) {
    int byte = (col << 1) ^ ((row & 7) << 4);
    return (row << 6) + (byte >> 1);
}

// Vt swizzle: slot bits from (d&6)|((d>>3)&1): write pairs and reads stay 2-way.
__device__ __forceinline__ int swz_v(int d, int kv) {
    int slot = (d & 6) | ((d >> 3) & 1);
    int byte = (kv << 1) ^ (slot << 4);
    return (d << 6) + (byte >> 1);
}

// ---------------------------------------------------------------------------
// fp32 -> bf16 convert: WEIGHTS ONLY (Wq,Wk,Wv,Wo). blockIdx.y selects array.
// ---------------------------------------------------------------------------
struct ConvArgs {
    const float*    src[4];
    unsigned short* dst[4];
    int             n4[4];
};

__global__ __launch_bounds__(256) void convert_kernel(ConvArgs a) {
    int z = blockIdx.y;
    const float4*   s = (const float4*)a.src[z];
    unsigned short* d = a.dst[z];
    int n = a.n4[z];
    for (int i = blockIdx.x * blockDim.x + threadIdx.x; i < n;
         i += gridDim.x * blockDim.x) {
        float4 v = s[i];
        ushort4 o;
        o.x = f2bf(v.x); o.y = f2bf(v.y); o.z = f2bf(v.z); o.w = f2bf(v.w);
        *(ushort4*)(d + 4L * i) = o;
    }
}

// ---------------------------------------------------------------------------
// proj GEMM v4 (best): 128x128 tile, BK=32, 4 waves, 256 threads, grid 768
// (3 blocks/CU). A = fp32 q/k/v fused-converted with the T14 split:
// PLOAD_A (4 float4/thread) at loop top, in flight across compute;
// PWRITE_A (4 cvt_pk + 2 ds_write_b128, linear layout) after barrier2.
// B via gload16. vmcnt(6) at barrier1 completes exactly B(cur)
// (outstanding = B(cur) 2 + A(nxt) 4 + B(nxt) 2). XCD-chunked grid.
// ---------------------------------------------------------------------------
__global__ __launch_bounds__(256) void proj_kernel(
    const float* __restrict__ xq, const float* __restrict__ xk,
    const float* __restrict__ xv, const unsigned short* __restrict__ wb,
    const float* __restrict__ bq, const float* __restrict__ bk,
    const float* __restrict__ bv, unsigned short* __restrict__ qkv) {
    __shared__ unsigned short As[2 * 128 * 32];   // 16 KB
    __shared__ unsigned short Bs[2 * 128 * 32];   // 16 KB

    const int t    = threadIdx.x;
    const int lane = t & 63;
    const int w    = t >> 6;
    const int wm   = w >> 1, wn = w & 1;
    const int l15  = lane & 15, g = lane >> 4;

    // XCD-chunked decode: 768 blocks; xcd owns M-tiles 4*xcd..4*xcd+3
    const int bid = blockIdx.x;
    const int xcd = bid & 7;
    const int k   = bid >> 3;            // 0..95 = 4(y) x 8(x) x 3(z)
    const int ty  = (xcd << 2) | (k & 3);
    const int tx  = (k >> 2) & 7;
    const int z   = k >> 5;
    const float* bias = (z == 0) ? bq : (z == 1) ? bk : bv;
    const float scale = (z == 0) ? QSCALE : 1.0f;

    const float* Af = (z == 0) ? xq : (z == 1) ? xk : xv;   // fp32 source
    const unsigned short* Bm = wb + (long)z * WE;
    unsigned short*       C  = qkv + (long)z * XE;
    const long m0 = (long)ty * 128;
    const long n0 = (long)tx * 128;
    const int  K  = D_MODEL;

    f32x4 acc[4][4] = {};

    // staging geometry: per matrix 512 16B-bf16-chunks; 2 per thread.
    // chunk idx: row = idx>>2, col = (idx&3)*8 (linear layout).
    const int idx0 = t, idx1 = t + 256;
    const int r0 = idx0 >> 2, c0 = (idx0 & 3) * 8;
    const int r1 = idx1 >> 2, c1 = (idx1 & 3) * 8;

    float4 a0_[2], a1_[2];   // in-flight fp32 A regs (issue-early)

#define PLOAD_A(k0)                                                        \
    {                                                                      \
        const float* s0 = Af + (m0 + r0) * K + (k0) + c0;                  \
        const float* s1 = Af + (m0 + r1) * K + (k0) + c1;                  \
        a0_[0] = *(const float4*)(s0);                                     \
        a1_[0] = *(const float4*)(s0 + 4);                                 \
        a0_[1] = *(const float4*)(s1);                                     \
        a1_[1] = *(const float4*)(s1 + 4);                                 \
    }

#define PSTAGE_B(k0, buf)                                                  \
    gload16(Bm + (n0 + r0) * K + (k0) + c0, &Bs[(buf) * 4096 + idx0 * 8]); \
    gload16(Bm + (n0 + r1) * K + (k0) + c1, &Bs[(buf) * 4096 + idx1 * 8]);

#define PWRITE_A(buf)                                                      \
    {                                                                      \
        uint4 pk;                                                          \
        pk.x = cvt_pk_bf16(a0_[0].x, a0_[0].y);                            \
        pk.y = cvt_pk_bf16(a0_[0].z, a0_[0].w);                            \
        pk.z = cvt_pk_bf16(a1_[0].x, a1_[0].y);                            \
        pk.w = cvt_pk_bf16(a1_[0].z, a1_[0].w);                            \
        *(uint4*)&As[(buf) * 4096 + idx0 * 8] = pk;                        \
        pk.x = cvt_pk_bf16(a0_[1].x, a0_[1].y);                            \
        pk.y = cvt_pk_bf16(a0_[1].z, a0_[1].w);                            \
        pk.z = cvt_pk_bf16(a1_[1].x, a1_[1].y);                            \
        pk.w = cvt_pk_bf16(a1_[1].z, a1_[1].w);                            \
        *(uint4*)&As[(buf) * 4096 + idx1 * 8] = pk;                        \
    }

    // ---- prologue: stage tile 0 into buffer 0 ----
    PLOAD_A(0);
    PSTAGE_B(0, 0);
    PWRITE_A(0);             // compiler waits the A regs; B stays in flight
    int cur = 0;

    for (int it = 0; it < K / 32; ++it) {           // 32 iters
        const int nxt = cur ^ 1;
        const int kn  = ((it + 1) * 32) & (K - 1);  // wrapped prefetch
        PLOAD_A(kn);         // A(nxt) -> regs, in flight across compute
        PSTAGE_B(kn, nxt);
        // outstanding: B(cur) 2 + A(nxt) 4 + B(nxt) 2 = 8; finish B(cur)
        asm volatile("s_waitcnt vmcnt(6)" ::: "memory");
        asm volatile("s_waitcnt lgkmcnt(0)" ::: "memory"); // A(cur) ds_writes
        __builtin_amdgcn_sched_barrier(0);
        __builtin_amdgcn_s_barrier();
        __builtin_amdgcn_sched_barrier(0);

        const unsigned short* Ab = &As[cur * 4096];
        const unsigned short* Bb = &Bs[cur * 4096];

        short8v af[4], bf_[4];
#pragma unroll
        for (int mf = 0; mf < 4; ++mf)
            af[mf] = *(const short8v*)&Ab[(wm * 64 + mf * 16 + l15) * 32 + g * 8];
#pragma unroll
        for (int nf = 0; nf < 4; ++nf)
            bf_[nf] = *(const short8v*)&Bb[(wn * 64 + nf * 16 + l15) * 32 + g * 8];
        __builtin_amdgcn_s_setprio(1);
#pragma unroll
        for (int mf = 0; mf < 4; ++mf)
#pragma unroll
            for (int nf = 0; nf < 4; ++nf)
                acc[mf][nf] = __builtin_amdgcn_mfma_f32_16x16x32_bf16(
                    af[mf], bf_[nf], acc[mf][nf], 0, 0, 0);
        __builtin_amdgcn_s_setprio(0);

        // ---- barrier2: all waves done READING buf cur (WAR fix) ----
        asm volatile("s_waitcnt lgkmcnt(0)" ::: "memory");
        __builtin_amdgcn_sched_barrier(0);
        __builtin_amdgcn_s_barrier();
        __builtin_amdgcn_sched_barrier(0);

        // ---- write A(nxt) into the freed buffer (regs arrived by now) ----
        PWRITE_A(nxt);
        cur = nxt;
    }

    // ---- epilogue: bias + scale, bf16 write ----
    float bvv[4];
#pragma unroll
    for (int nf = 0; nf < 4; ++nf)
        bvv[nf] = bias[n0 + wn * 64 + nf * 16 + l15];

#pragma unroll
    for (int mf = 0; mf < 4; ++mf)
#pragma unroll
        for (int nf = 0; nf < 4; ++nf)
#pragma unroll
            for (int r = 0; r < 4; ++r) {
                long row = m0 + wm * 64 + mf * 16 + g * 4 + r;
                long col = n0 + wn * 64 + nf * 16 + l15;
                C[row * (long)D_MODEL + col] =
                    f2bf((acc[mf][nf][r] + bvv[nf]) * scale);
            }
#undef PLOAD_A
#undef PSTAGE_B
#undef PWRITE_A
}

// ---------------------------------------------------------------------------
// out GEMM: proven 128x128/BK=32 core, XCD-chunked, 256 blocks.
// ---------------------------------------------------------------------------
__global__ __launch_bounds__(256) void out_kernel(
    const unsigned short* __restrict__ ob, const unsigned short* __restrict__ wo,
    const float* __restrict__ bo, float* __restrict__ out) {
    __shared__ unsigned short As[128 * 32];
    __shared__ unsigned short Bs[128 * 32];

    const int t    = threadIdx.x;
    const int lane = t & 63;
    const int w    = t >> 6;
    const int wm   = w >> 1, wn = w & 1;
    const int l15  = lane & 15, g = lane >> 4;

    const int bid = blockIdx.x;
    const int xcd = bid & 7;
    const int k   = bid >> 3;            // 0..31 = 4(y) x 8(x)
    const long m0 = (long)((xcd << 2) | (k & 3)) * 128;
    const long n0 = (long)(k >> 2) * 128;
    const int  K  = D_MODEL, N = D_MODEL;

    f32x4 acc[4][4] = {};

    const int idx0 = t, idx1 = t + 256;
    const int r0 = idx0 >> 2, c0 = (idx0 & 3) * 8;
    const int r1 = idx1 >> 2, c1 = (idx1 & 3) * 8;
    const unsigned short* pa0 = ob + (m0 + r0) * K + c0;
    const unsigned short* pa1 = ob + (m0 + r1) * K + c1;
    const unsigned short* pb0 = wo + (n0 + r0) * K + c0;
    const unsigned short* pb1 = wo + (n0 + r1) * K + c1;

    for (int k0 = 0; k0 < K; k0 += 32) {
        gload16(pa0 + k0, &As[idx0 * 8]);
        gload16(pa1 + k0, &As[idx1 * 8]);
        gload16(pb0 + k0, &Bs[idx0 * 8]);
        gload16(pb1 + k0, &Bs[idx1 * 8]);
        __syncthreads();

        short8v af[4], bf_[4];
#pragma unroll
        for (int mf = 0; mf < 4; ++mf)
            af[mf] = *(const short8v*)&As[(wm * 64 + mf * 16 + l15) * 32 + g * 8];
#pragma unroll
        for (int nf = 0; nf < 4; ++nf)
            bf_[nf] = *(const short8v*)&Bs[(wn * 64 + nf * 16 + l15) * 32 + g * 8];
#pragma unroll
        for (int mf = 0; mf < 4; ++mf)
#pragma unroll
            for (int nf = 0; nf < 4; ++nf)
                acc[mf][nf] = __builtin_amdgcn_mfma_f32_16x16x32_bf16(
                    af[mf], bf_[nf], acc[mf][nf], 0, 0, 0);
        __syncthreads();
    }

    float bvv[4];
#pragma unroll
    for (int nf = 0; nf < 4; ++nf)
        bvv[nf] = bo[n0 + wn * 64 + nf * 16 + l15];

#pragma unroll
    for (int mf = 0; mf < 4; ++mf)
#pragma unroll
        for (int nf = 0; nf < 4; ++nf)
#pragma unroll
            for (int r = 0; r < 4; ++r) {
                long row = m0 + wm * 64 + mf * 16 + g * 4 + r;
                long col = n0 + wn * 64 + nf * 16 + l15;
                out[row * (long)N + col] = acc[mf][nf][r] + bvv[nf];
            }
}

// ---------------------------------------------------------------------------
// Flash attention v4b + XCD-chunked grid (measured 63.0-63.4 us).
// ---------------------------------------------------------------------------
#define KVB 4096   // elems per K/V buffer (64 rows x 64)

__global__ __launch_bounds__(512) void attn_kernel(
    const unsigned short* __restrict__ Qb, const unsigned short* __restrict__ Kb,
    const unsigned short* __restrict__ Vb, unsigned short* __restrict__ Ob) {
    __shared__ alignas(16) unsigned short Ks[2 * KVB];     // 16 KB
    __shared__ alignas(16) unsigned short Vt[2 * KVB];     // 16 KB  V^T [d][kv]
    __shared__ alignas(16) unsigned short Ps[8][16 * 64];  // 16 KB  per-wave P
    __shared__ alignas(16) float corrS[8][16];

    const int t = threadIdx.x, lane = t & 63, w = t >> 6;
    const int l15 = lane & 15, g = lane >> 4;
    const int bid = blockIdx.x;
    const int xcd = bid & 7;
    const int kk2 = bid >> 3;              // 0..63
    const int bh  = (xcd << 2) | (kk2 & 3);
    const int qb  = kk2 >> 2;              // 0..15
    const long headoff = (long)(bh >> 4) * SEQ * D_MODEL + (long)(bh & 15) * DKH;
    const int q0w = qb * 128 + w * 16;

    short8v qf[2];
#pragma unroll
    for (int ks = 0; ks < 2; ++ks)
        qf[ks] = *(const short8v*)(Qb + headoff +
            (long)(q0w + l15) * D_MODEL + ks * 32 + g * 8);

    short8v onesv;
#pragma unroll
    for (int j = 0; j < 8; ++j) onesv[j] = (short)0x3F80;

    f32x4 o[4] = {};
    f32x4 ol = {};
    float mrun = -3.0e38f;

    const int vd0  = (t & 31) * 2;
    const int vkv0 = (t >> 5) * 4;
    const int kr0 = t >> 3, ks0 = t & 7;

    unsigned int va[4];

#define ISSUE_V(kt)                                                        \
    _Pragma("unroll")                                                      \
    for (int j = 0; j < 4; ++j)                                            \
        va[j] = *(const unsigned int*)(Vb + headoff +                      \
            (long)((kt) + vkv0 + j) * D_MODEL + vd0);

#define ISSUE_K(kt, off)                                                   \
    gload16(Kb + headoff + (long)((kt) + kr0) * D_MODEL +                  \
                ((ks0 ^ (kr0 & 7)) << 3), &Ks[(off) + t * 8]);

#define WRITE_V(off)                                                       \
    {                                                                      \
        short4v ra, rb;                                                    \
        _Pragma("unroll")                                                  \
        for (int j = 0; j < 4; ++j) {                                      \
            ra[j] = (short)(va[j] & 0xffffu);                              \
            rb[j] = (short)(va[j] >> 16);                                  \
        }                                                                  \
        *(short4v*)&Vt[(off) + swz_v(vd0,     vkv0)] = ra;                 \
        *(short4v*)&Vt[(off) + swz_v(vd0 + 1, vkv0)] = rb;                 \
    }

    asm volatile("s_waitcnt vmcnt(0)" ::: "memory");
    ISSUE_V(0);
    ISSUE_K(0, 0);
    WRITE_V(0);
    int cur = 0;

    for (int it = 0; it < SEQ / 64; ++it) {
        const int nxt = cur ^ 1;
        const int ktn = (((it + 1) & (SEQ / 64 - 1))) * 64;
        ISSUE_V(ktn);
        ISSUE_K(ktn, nxt * KVB);
        asm volatile("s_waitcnt vmcnt(5)" ::: "memory");
        asm volatile("s_waitcnt lgkmcnt(0)" ::: "memory");
        __builtin_amdgcn_sched_barrier(0);
        __builtin_amdgcn_s_barrier();
        __builtin_amdgcn_sched_barrier(0);

        const int kO = cur * KVB;

        f32x4 st[4] = {};
        __builtin_amdgcn_s_setprio(1);
#pragma unroll
        for (int ks = 0; ks < 2; ++ks)
#pragma unroll
            for (int mf = 0; mf < 4; ++mf) {
                short8v kf = *(const short8v*)&Ks[kO + swz_u(mf * 16 + l15, ks * 32 + g * 8)];
                st[mf] = __builtin_amdgcn_mfma_f32_16x16x32_bf16(
                    kf, qf[ks], st[mf], 0, 0, 0);
            }
        __builtin_amdgcn_s_setprio(0);

        float vmax = st[0][0];
#pragma unroll
        for (int mf = 0; mf < 4; ++mf)
#pragma unroll
            for (int r = 0; r < 4; ++r)
                vmax = fmaxf(vmax, st[mf][r]);
        vmax = fmaxf(vmax, __shfl_xor(vmax, 16));
        vmax = fmaxf(vmax, __shfl_xor(vmax, 32));

        const bool grow = __any(vmax > mrun + 8.0f);
        if (grow) {
            float mnew = fmaxf(mrun, vmax);
            float corr = fexp2(mrun - mnew);
            mrun = mnew;
            if (g == 0) corrS[w][l15] = corr;
        }

#pragma unroll
        for (int mf = 0; mf < 4; ++mf)
#pragma unroll
            for (int r = 0; r < 4; ++r)
                st[mf][r] = fexp2(st[mf][r] - mrun);

        unsigned short* Pw = Ps[w];
#pragma unroll
        for (int mf = 0; mf < 4; ++mf) {
            uint2 pk;
            pk.x = cvt_pk_bf16(st[mf][0], st[mf][1]);
            pk.y = cvt_pk_bf16(st[mf][2], st[mf][3]);
            *(uint2*)&Pw[swz_u(l15, mf * 16 + g * 4)] = pk;
        }

        if (grow) {
            float4 cv = *(const float4*)&corrS[w][g * 4];
#pragma unroll
            for (int nd = 0; nd < 4; ++nd)
#pragma unroll
                for (int r = 0; r < 4; ++r)
                    o[nd][r] *= cv[r];
#pragma unroll
            for (int r = 0; r < 4; ++r) ol[r] *= cv[r];
        }

        __builtin_amdgcn_s_setprio(1);
#pragma unroll
        for (int ks2 = 0; ks2 < 2; ++ks2) {
            short8v pf = *(const short8v*)&Pw[swz_u(l15, ks2 * 32 + g * 8)];
            ol = __builtin_amdgcn_mfma_f32_16x16x32_bf16(
                pf, onesv, ol, 0, 0, 0);
#pragma unroll
            for (int nd = 0; nd < 4; ++nd) {
                short8v vf = *(const short8v*)&Vt[kO + swz_v(nd * 16 + l15, ks2 * 32 + g * 8)];
                o[nd] = __builtin_amdgcn_mfma_f32_16x16x32_bf16(
                    pf, vf, o[nd], 0, 0, 0);
            }
        }
        __builtin_amdgcn_s_setprio(0);

        WRITE_V(nxt * KVB);
        cur = nxt;
    }

#pragma unroll
    for (int r = 0; r < 4; ++r) {
        float inv = 1.f / (ol[r] + 1e-9f);
        long rowoff = headoff + (long)(q0w + g * 4 + r) * D_MODEL;
#pragma unroll
        for (int nd = 0; nd < 4; ++nd)
            Ob[rowoff + nd * 16 + l15] = f2bf(o[nd][r] * inv);
    }
#undef ISSUE_V
#undef ISSUE_K
#undef WRITE_V
}

// ---------------------------------------------------------------------------
// Launch
// ---------------------------------------------------------------------------
extern "C" void kernel_launch(void* const* d_in, const int* in_sizes, int n_in,
                              void* d_out, int out_size, void* d_ws, size_t ws_size,
                              hipStream_t stream) {
    // d_in order: 0 q, 1 k, 2 v, 3 Wq, 4 bq, 5 Wk, 6 bk, 7 Wv, 8 bv, 9 Wo, 10 bo
    unsigned short* ws  = (unsigned short*)d_ws;
    unsigned short* wb  = ws;                       // 4*WE  bf16 weights
    unsigned short* qkv = ws + 4L * WE;             // 3*XE  Q(scaled), K, V
    unsigned short* ob  = qkv + 3L * XE;            // XE    attention output

    ConvArgs ca;
    ca.src[0] = (const float*)d_in[3]; ca.dst[0] = wb;           ca.n4[0] = (int)(WE / 4);
    ca.src[1] = (const float*)d_in[5]; ca.dst[1] = wb + WE;      ca.n4[1] = (int)(WE / 4);
    ca.src[2] = (const float*)d_in[7]; ca.dst[2] = wb + 2L * WE; ca.n4[2] = (int)(WE / 4);
    ca.src[3] = (const float*)d_in[9]; ca.dst[3] = wb + 3L * WE; ca.n4[3] = (int)(WE / 4);

    hipLaunchKernelGGL(convert_kernel, dim3(512, 4), dim3(256), 0, stream, ca);

    hipLaunchKernelGGL(proj_kernel, dim3(768), dim3(256), 0, stream,
                       (const float*)d_in[0], (const float*)d_in[1],
                       (const float*)d_in[2], wb,
                       (const float*)d_in[4], (const float*)d_in[6],
                       (const float*)d_in[8], qkv);

    hipLaunchKernelGGL(attn_kernel, dim3(512), dim3(512), 0, stream,
                       qkv, qkv + XE, qkv + 2L * XE, ob);

    hipLaunchKernelGGL(out_kernel, dim3(256), dim3(256), 0, stream,
                       ob, wb + 3L * WE, (const float*)d_in[10], (float*)d_out);
}

// Round 35
// 127.864 us; speedup vs baseline: 1.0024x; 1.0024x over previous
//
#include <hip/hip_runtime.h>

// ---------------------------------------------------------------------------
// MultiHeadAttention forward, MI355X (gfx950).
// Weights-only fp32->bf16 convert; Q/K/V projections (128x128/BK=32 GEMM,
// grid 768 = 3 blocks/CU, A = fp32 fused-convert with T14 split, B = bf16
// weights via global_load_lds, dual-barrier counted-vmcnt dbuf pipeline,
// XCD-chunked); flash attention v4b + XCD-chunked grid; output projection.
// (Converged best: 127.2-128.2 us across 6 runs.)
// ---------------------------------------------------------------------------

#define D_MODEL 1024
#define NHEADS  16
#define DKH     64
#define SEQ     2048
#define BATCH   2
#define MTOT    (BATCH * SEQ)            // 4096 rows
#define XE      ((long)MTOT * D_MODEL)   // 4194304 elems
#define WE      ((long)D_MODEL * D_MODEL)
#define QSCALE  0.18033688011112042f     // 0.125 * log2(e): softmax in exp2 domain

typedef __attribute__((ext_vector_type(8))) short short8v;   // 8 x bf16 (4 VGPR)
typedef __attribute__((ext_vector_type(4))) short short4v;   // 4 x bf16
typedef __attribute__((ext_vector_type(4))) float f32x4;     // MFMA C/D frag

typedef __attribute__((address_space(1))) void as1_void;
typedef __attribute__((address_space(3))) void as3_void;

__device__ __forceinline__ void gload16(const void* g, void* l) {
    __builtin_amdgcn_global_load_lds((const as1_void*)g, (as3_void*)l, 16, 0, 0);
}

__device__ __forceinline__ unsigned short f2bf(float x) {
    unsigned int u = __float_as_uint(x);
    u += 0x7FFFu + ((u >> 16) & 1u);     // RNE
    return (unsigned short)(u >> 16);
}

// native v_exp_f32: computes 2^x (avoid __exp2f: glibc name collision)
__device__ __forceinline__ float fexp2(float x) {
    return __builtin_amdgcn_exp2f(x);
}

// hardware packed f32x2 -> bf16x2 (RNE; one VALU op for two converts)
__device__ __forceinline__ unsigned int cvt_pk_bf16(float lo, float hi) {
    unsigned int r;
    asm("v_cvt_pk_bf16_f32 %0, %1, %2" : "=v"(r) : "v"(lo), "v"(hi));
    return r;
}

// XOR swizzle for [rows][64 bf16] LDS tiles (128B rows).
__device__ __forceinline__ int swz_u(int row, int col) {
    int byte = (col << 1) ^ ((row & 7) << 4);
    return (row << 6) + (byte >> 1);
}

// Vt swizzle: slot bits from (d&6)|((d>>3)&1): write pairs and reads stay 2-way.
__device__ __forceinline__ int swz_v(int d, int kv) {
    int slot = (d & 6) | ((d >> 3) & 1);
    int byte = (kv << 1) ^ (slot << 4);
    return (d << 6) + (byte >> 1);
}

// ---------------------------------------------------------------------------
// fp32 -> bf16 convert: WEIGHTS ONLY (Wq,Wk,Wv,Wo). blockIdx.y selects array.
// ---------------------------------------------------------------------------
struct ConvArgs {
    const float*    src[4];
    unsigned short* dst[4];
    int             n4[4];
};

__global__ __launch_bounds__(256) void convert_kernel(ConvArgs a) {
    int z = blockIdx.y;
    const float4*   s = (const float4*)a.src[z];
    unsigned short* d = a.dst[z];
    int n = a.n4[z];
    for (int i = blockIdx.x * blockDim.x + threadIdx.x; i < n;
         i += gridDim.x * blockDim.x) {
        float4 v = s[i];
        ushort4 o;
        o.x = f2bf(v.x); o.y = f2bf(v.y); o.z = f2bf(v.z); o.w = f2bf(v.w);
        *(ushort4*)(d + 4L * i) = o;
    }
}

// ---------------------------------------------------------------------------
// proj GEMM v4 (best): 128x128 tile, BK=32, 4 waves, 256 threads, grid 768
// (3 blocks/CU). A = fp32 q/k/v fused-converted with the T14 split:
// PLOAD_A (4 float4/thread) at loop top, in flight across compute;
// PWRITE_A (4 cvt_pk + 2 ds_write_b128, linear layout) after barrier2.
// B via gload16. vmcnt(6) at barrier1 completes exactly B(cur)
// (outstanding = B(cur) 2 + A(nxt) 4 + B(nxt) 2). XCD-chunked grid.
// ---------------------------------------------------------------------------
__global__ __launch_bounds__(256) void proj_kernel(
    const float* __restrict__ xq, const float* __restrict__ xk,
    const float* __restrict__ xv, const unsigned short* __restrict__ wb,
    const float* __restrict__ bq, const float* __restrict__ bk,
    const float* __restrict__ bv, unsigned short* __restrict__ qkv) {
    __shared__ unsigned short As[2 * 128 * 32];   // 16 KB
    __shared__ unsigned short Bs[2 * 128 * 32];   // 16 KB

    const int t    = threadIdx.x;
    const int lane = t & 63;
    const int w    = t >> 6;
    const int wm   = w >> 1, wn = w & 1;
    const int l15  = lane & 15, g = lane >> 4;

    // XCD-chunked decode: 768 blocks; xcd owns M-tiles 4*xcd..4*xcd+3
    const int bid = blockIdx.x;
    const int xcd = bid & 7;
    const int k   = bid >> 3;            // 0..95 = 4(y) x 8(x) x 3(z)
    const int ty  = (xcd << 2) | (k & 3);
    const int tx  = (k >> 2) & 7;
    const int z   = k >> 5;
    const float* bias = (z == 0) ? bq : (z == 1) ? bk : bv;
    const float scale = (z == 0) ? QSCALE : 1.0f;

    const float* Af = (z == 0) ? xq : (z == 1) ? xk : xv;   // fp32 source
    const unsigned short* Bm = wb + (long)z * WE;
    unsigned short*       C  = qkv + (long)z * XE;
    const long m0 = (long)ty * 128;
    const long n0 = (long)tx * 128;
    const int  K  = D_MODEL;

    f32x4 acc[4][4] = {};

    // staging geometry: per matrix 512 16B-bf16-chunks; 2 per thread.
    // chunk idx: row = idx>>2, col = (idx&3)*8 (linear layout).
    const int idx0 = t, idx1 = t + 256;
    const int r0 = idx0 >> 2, c0 = (idx0 & 3) * 8;
    const int r1 = idx1 >> 2, c1 = (idx1 & 3) * 8;

    float4 a0_[2], a1_[2];   // in-flight fp32 A regs (issue-early)

#define PLOAD_A(k0)                                                        \
    {                                                                      \
        const float* s0 = Af + (m0 + r0) * K + (k0) + c0;                  \
        const float* s1 = Af + (m0 + r1) * K + (k0) + c1;                  \
        a0_[0] = *(const float4*)(s0);                                     \
        a1_[0] = *(const float4*)(s0 + 4);                                 \
        a0_[1] = *(const float4*)(s1);                                     \
        a1_[1] = *(const float4*)(s1 + 4);                                 \
    }

#define PSTAGE_B(k0, buf)                                                  \
    gload16(Bm + (n0 + r0) * K + (k0) + c0, &Bs[(buf) * 4096 + idx0 * 8]); \
    gload16(Bm + (n0 + r1) * K + (k0) + c1, &Bs[(buf) * 4096 + idx1 * 8]);

#define PWRITE_A(buf)                                                      \
    {                                                                      \
        uint4 pk;                                                          \
        pk.x = cvt_pk_bf16(a0_[0].x, a0_[0].y);                            \
        pk.y = cvt_pk_bf16(a0_[0].z, a0_[0].w);                            \
        pk.z = cvt_pk_bf16(a1_[0].x, a1_[0].y);                            \
        pk.w = cvt_pk_bf16(a1_[0].z, a1_[0].w);                            \
        *(uint4*)&As[(buf) * 4096 + idx0 * 8] = pk;                        \
        pk.x = cvt_pk_bf16(a0_[1].x, a0_[1].y);                            \
        pk.y = cvt_pk_bf16(a0_[1].z, a0_[1].w);                            \
        pk.z = cvt_pk_bf16(a1_[1].x, a1_[1].y);                            \
        pk.w = cvt_pk_bf16(a1_[1].z, a1_[1].w);                            \
        *(uint4*)&As[(buf) * 4096 + idx1 * 8] = pk;                        \
    }

    // ---- prologue: stage tile 0 into buffer 0 ----
    PLOAD_A(0);
    PSTAGE_B(0, 0);
    PWRITE_A(0);             // compiler waits the A regs; B stays in flight
    int cur = 0;

    for (int it = 0; it < K / 32; ++it) {           // 32 iters
        const int nxt = cur ^ 1;
        const int kn  = ((it + 1) * 32) & (K - 1);  // wrapped prefetch
        PLOAD_A(kn);         // A(nxt) -> regs, in flight across compute
        PSTAGE_B(kn, nxt);
        // outstanding: B(cur) 2 + A(nxt) 4 + B(nxt) 2 = 8; finish B(cur)
        asm volatile("s_waitcnt vmcnt(6)" ::: "memory");
        asm volatile("s_waitcnt lgkmcnt(0)" ::: "memory"); // A(cur) ds_writes
        __builtin_amdgcn_sched_barrier(0);
        __builtin_amdgcn_s_barrier();
        __builtin_amdgcn_sched_barrier(0);

        const unsigned short* Ab = &As[cur * 4096];
        const unsigned short* Bb = &Bs[cur * 4096];

        short8v af[4], bf_[4];
#pragma unroll
        for (int mf = 0; mf < 4; ++mf)
            af[mf] = *(const short8v*)&Ab[(wm * 64 + mf * 16 + l15) * 32 + g * 8];
#pragma unroll
        for (int nf = 0; nf < 4; ++nf)
            bf_[nf] = *(const short8v*)&Bb[(wn * 64 + nf * 16 + l15) * 32 + g * 8];
        __builtin_amdgcn_s_setprio(1);
#pragma unroll
        for (int mf = 0; mf < 4; ++mf)
#pragma unroll
            for (int nf = 0; nf < 4; ++nf)
                acc[mf][nf] = __builtin_amdgcn_mfma_f32_16x16x32_bf16(
                    af[mf], bf_[nf], acc[mf][nf], 0, 0, 0);
        __builtin_amdgcn_s_setprio(0);

        // ---- barrier2: all waves done READING buf cur (WAR fix) ----
        asm volatile("s_waitcnt lgkmcnt(0)" ::: "memory");
        __builtin_amdgcn_sched_barrier(0);
        __builtin_amdgcn_s_barrier();
        __builtin_amdgcn_sched_barrier(0);

        // ---- write A(nxt) into the freed buffer (regs arrived by now) ----
        PWRITE_A(nxt);
        cur = nxt;
    }

    // ---- epilogue: bias + scale, bf16 write ----
    float bvv[4];
#pragma unroll
    for (int nf = 0; nf < 4; ++nf)
        bvv[nf] = bias[n0 + wn * 64 + nf * 16 + l15];

#pragma unroll
    for (int mf = 0; mf < 4; ++mf)
#pragma unroll
        for (int nf = 0; nf < 4; ++nf)
#pragma unroll
            for (int r = 0; r < 4; ++r) {
                long row = m0 + wm * 64 + mf * 16 + g * 4 + r;
                long col = n0 + wn * 64 + nf * 16 + l15;
                C[row * (long)D_MODEL + col] =
                    f2bf((acc[mf][nf][r] + bvv[nf]) * scale);
            }
#undef PLOAD_A
#undef PSTAGE_B
#undef PWRITE_A
}

// ---------------------------------------------------------------------------
// out GEMM: proven 128x128/BK=32 core, XCD-chunked, 256 blocks.
// ---------------------------------------------------------------------------
__global__ __launch_bounds__(256) void out_kernel(
    const unsigned short* __restrict__ ob, const unsigned short* __restrict__ wo,
    const float* __restrict__ bo, float* __restrict__ out) {
    __shared__ unsigned short As[128 * 32];
    __shared__ unsigned short Bs[128 * 32];

    const int t    = threadIdx.x;
    const int lane = t & 63;
    const int w    = t >> 6;
    const int wm   = w >> 1, wn = w & 1;
    const int l15  = lane & 15, g = lane >> 4;

    const int bid = blockIdx.x;
    const int xcd = bid & 7;
    const int k   = bid >> 3;            // 0..31 = 4(y) x 8(x)
    const long m0 = (long)((xcd << 2) | (k & 3)) * 128;
    const long n0 = (long)(k >> 2) * 128;
    const int  K  = D_MODEL, N = D_MODEL;

    f32x4 acc[4][4] = {};

    const int idx0 = t, idx1 = t + 256;
    const int r0 = idx0 >> 2, c0 = (idx0 & 3) * 8;
    const int r1 = idx1 >> 2, c1 = (idx1 & 3) * 8;
    const unsigned short* pa0 = ob + (m0 + r0) * K + c0;
    const unsigned short* pa1 = ob + (m0 + r1) * K + c1;
    const unsigned short* pb0 = wo + (n0 + r0) * K + c0;
    const unsigned short* pb1 = wo + (n0 + r1) * K + c1;

    for (int k0 = 0; k0 < K; k0 += 32) {
        gload16(pa0 + k0, &As[idx0 * 8]);
        gload16(pa1 + k0, &As[idx1 * 8]);
        gload16(pb0 + k0, &Bs[idx0 * 8]);
        gload16(pb1 + k0, &Bs[idx1 * 8]);
        __syncthreads();

        short8v af[4], bf_[4];
#pragma unroll
        for (int mf = 0; mf < 4; ++mf)
            af[mf] = *(const short8v*)&As[(wm * 64 + mf * 16 + l15) * 32 + g * 8];
#pragma unroll
        for (int nf = 0; nf < 4; ++nf)
            bf_[nf] = *(const short8v*)&Bs[(wn * 64 + nf * 16 + l15) * 32 + g * 8];
#pragma unroll
        for (int mf = 0; mf < 4; ++mf)
#pragma unroll
            for (int nf = 0; nf < 4; ++nf)
                acc[mf][nf] = __builtin_amdgcn_mfma_f32_16x16x32_bf16(
                    af[mf], bf_[nf], acc[mf][nf], 0, 0, 0);
        __syncthreads();
    }

    float bvv[4];
#pragma unroll
    for (int nf = 0; nf < 4; ++nf)
        bvv[nf] = bo[n0 + wn * 64 + nf * 16 + l15];

#pragma unroll
    for (int mf = 0; mf < 4; ++mf)
#pragma unroll
        for (int nf = 0; nf < 4; ++nf)
#pragma unroll
            for (int r = 0; r < 4; ++r) {
                long row = m0 + wm * 64 + mf * 16 + g * 4 + r;
                long col = n0 + wn * 64 + nf * 16 + l15;
                out[row * (long)N + col] = acc[mf][nf][r] + bvv[nf];
            }
}

// ---------------------------------------------------------------------------
// Flash attention v4b + XCD-chunked grid (measured 63.0-63.8 us).
// ---------------------------------------------------------------------------
#define KVB 4096   // elems per K/V buffer (64 rows x 64)

__global__ __launch_bounds__(512) void attn_kernel(
    const unsigned short* __restrict__ Qb, const unsigned short* __restrict__ Kb,
    const unsigned short* __restrict__ Vb, unsigned short* __restrict__ Ob) {
    __shared__ alignas(16) unsigned short Ks[2 * KVB];     // 16 KB
    __shared__ alignas(16) unsigned short Vt[2 * KVB];     // 16 KB  V^T [d][kv]
    __shared__ alignas(16) unsigned short Ps[8][16 * 64];  // 16 KB  per-wave P
    __shared__ alignas(16) float corrS[8][16];

    const int t = threadIdx.x, lane = t & 63, w = t >> 6;
    const int l15 = lane & 15, g = lane >> 4;
    const int bid = blockIdx.x;
    const int xcd = bid & 7;
    const int kk2 = bid >> 3;              // 0..63
    const int bh  = (xcd << 2) | (kk2 & 3);
    const int qb  = kk2 >> 2;              // 0..15
    const long headoff = (long)(bh >> 4) * SEQ * D_MODEL + (long)(bh & 15) * DKH;
    const int q0w = qb * 128 + w * 16;

    short8v qf[2];
#pragma unroll
    for (int ks = 0; ks < 2; ++ks)
        qf[ks] = *(const short8v*)(Qb + headoff +
            (long)(q0w + l15) * D_MODEL + ks * 32 + g * 8);

    short8v onesv;
#pragma unroll
    for (int j = 0; j < 8; ++j) onesv[j] = (short)0x3F80;

    f32x4 o[4] = {};
    f32x4 ol = {};
    float mrun = -3.0e38f;

    const int vd0  = (t & 31) * 2;
    const int vkv0 = (t >> 5) * 4;
    const int kr0 = t >> 3, ks0 = t & 7;

    unsigned int va[4];

#define ISSUE_V(kt)                                                        \
    _Pragma("unroll")                                                      \
    for (int j = 0; j < 4; ++j)                                            \
        va[j] = *(const unsigned int*)(Vb + headoff +                      \
            (long)((kt) + vkv0 + j) * D_MODEL + vd0);

#define ISSUE_K(kt, off)                                                   \
    gload16(Kb + headoff + (long)((kt) + kr0) * D_MODEL +                  \
                ((ks0 ^ (kr0 & 7)) << 3), &Ks[(off) + t * 8]);

#define WRITE_V(off)                                                       \
    {                                                                      \
        short4v ra, rb;                                                    \
        _Pragma("unroll")                                                  \
        for (int j = 0; j < 4; ++j) {                                      \
            ra[j] = (short)(va[j] & 0xffffu);                              \
            rb[j] = (short)(va[j] >> 16);                                  \
        }                                                                  \
        *(short4v*)&Vt[(off) + swz_v(vd0,     vkv0)] = ra;                 \
        *(short4v*)&Vt[(off) + swz_v(vd0 + 1, vkv0)] = rb;                 \
    }

    asm volatile("s_waitcnt vmcnt(0)" ::: "memory");
    ISSUE_V(0);
    ISSUE_K(0, 0);
    WRITE_V(0);
    int cur = 0;

    for (int it = 0; it < SEQ / 64; ++it) {
        const int nxt = cur ^ 1;
        const int ktn = (((it + 1) & (SEQ / 64 - 1))) * 64;
        ISSUE_V(ktn);
        ISSUE_K(ktn, nxt * KVB);
        asm volatile("s_waitcnt vmcnt(5)" ::: "memory");
        asm volatile("s_waitcnt lgkmcnt(0)" ::: "memory");
        __builtin_amdgcn_sched_barrier(0);
        __builtin_amdgcn_s_barrier();
        __builtin_amdgcn_sched_barrier(0);

        const int kO = cur * KVB;

        f32x4 st[4] = {};
        __builtin_amdgcn_s_setprio(1);
#pragma unroll
        for (int ks = 0; ks < 2; ++ks)
#pragma unroll
            for (int mf = 0; mf < 4; ++mf) {
                short8v kf = *(const short8v*)&Ks[kO + swz_u(mf * 16 + l15, ks * 32 + g * 8)];
                st[mf] = __builtin_amdgcn_mfma_f32_16x16x32_bf16(
                    kf, qf[ks], st[mf], 0, 0, 0);
            }
        __builtin_amdgcn_s_setprio(0);

        float vmax = st[0][0];
#pragma unroll
        for (int mf = 0; mf < 4; ++mf)
#pragma unroll
            for (int r = 0; r < 4; ++r)
                vmax = fmaxf(vmax, st[mf][r]);
        vmax = fmaxf(vmax, __shfl_xor(vmax, 16));
        vmax = fmaxf(vmax, __shfl_xor(vmax, 32));

        const bool grow = __any(vmax > mrun + 8.0f);
        if (grow) {
            float mnew = fmaxf(mrun, vmax);
            float corr = fexp2(mrun - mnew);
            mrun = mnew;
            if (g == 0) corrS[w][l15] = corr;
        }

#pragma unroll
        for (int mf = 0; mf < 4; ++mf)
#pragma unroll
            for (int r = 0; r < 4; ++r)
                st[mf][r] = fexp2(st[mf][r] - mrun);

        unsigned short* Pw = Ps[w];
#pragma unroll
        for (int mf = 0; mf < 4; ++mf) {
            uint2 pk;
            pk.x = cvt_pk_bf16(st[mf][0], st[mf][1]);
            pk.y = cvt_pk_bf16(st[mf][2], st[mf][3]);
            *(uint2*)&Pw[swz_u(l15, mf * 16 + g * 4)] = pk;
        }

        if (grow) {
            float4 cv = *(const float4*)&corrS[w][g * 4];
#pragma unroll
            for (int nd = 0; nd < 4; ++nd)
#pragma unroll
                for (int r = 0; r < 4; ++r)
                    o[nd][r] *= cv[r];
#pragma unroll
            for (int r = 0; r < 4; ++r) ol[r] *= cv[r];
        }

        __builtin_amdgcn_s_setprio(1);
#pragma unroll
        for (int ks2 = 0; ks2 < 2; ++ks2) {
            short8v pf = *(const short8v*)&Pw[swz_u(l15, ks2 * 32 + g * 8)];
            ol = __builtin_amdgcn_mfma_f32_16x16x32_bf16(
                pf, onesv, ol, 0, 0, 0);
#pragma unroll
            for (int nd = 0; nd < 4; ++nd) {
                short8v vf = *(const short8v*)&Vt[kO + swz_v(nd * 16 + l15, ks2 * 32 + g * 8)];
                o[nd] = __builtin_amdgcn_mfma_f32_16x16x32_bf16(
                    pf, vf, o[nd], 0, 0, 0);
            }
        }
        __builtin_amdgcn_s_setprio(0);

        WRITE_V(nxt * KVB);
        cur = nxt;
    }

#pragma unroll
    for (int r = 0; r < 4; ++r) {
        float inv = 1.f / (ol[r] + 1e-9f);
        long rowoff = headoff + (long)(q0w + g * 4 + r) * D_MODEL;
#pragma unroll
        for (int nd = 0; nd < 4; ++nd)
            Ob[rowoff + nd * 16 + l15] = f2bf(o[nd][r] * inv);
    }
#undef ISSUE_V
#undef ISSUE_K
#undef WRITE_V
}

// ---------------------------------------------------------------------------
// Launch
// ---------------------------------------------------------------------------
extern "C" void kernel_launch(void* const* d_in, const int* in_sizes, int n_in,
                              void* d_out, int out_size, void* d_ws, size_t ws_size,
                              hipStream_t stream) {
    // d_in order: 0 q, 1 k, 2 v, 3 Wq, 4 bq, 5 Wk, 6 bk, 7 Wv, 8 bv, 9 Wo, 10 bo
    unsigned short* ws  = (unsigned short*)d_ws;
    unsigned short* wb  = ws;                       // 4*WE  bf16 weights
    unsigned short* qkv = ws + 4L * WE;             // 3*XE  Q(scaled), K, V
    unsigned short* ob  = qkv + 3L * XE;            // XE    attention output

    ConvArgs ca;
    ca.src[0] = (const float*)d_in[3]; ca.dst[0] = wb;           ca.n4[0] = (int)(WE / 4);
    ca.src[1] = (const float*)d_in[5]; ca.dst[1] = wb + WE;      ca.n4[1] = (int)(WE / 4);
    ca.src[2] = (const float*)d_in[7]; ca.dst[2] = wb + 2L * WE; ca.n4[2] = (int)(WE / 4);
    ca.src[3] = (const float*)d_in[9]; ca.dst[3] = wb + 3L * WE; ca.n4[3] = (int)(WE / 4);

    hipLaunchKernelGGL(convert_kernel, dim3(512, 4), dim3(256), 0, stream, ca);

    hipLaunchKernelGGL(proj_kernel, dim3(768), dim3(256), 0, stream,
                       (const float*)d_in[0], (const float*)d_in[1],
                       (const float*)d_in[2], wb,
                       (const float*)d_in[4], (const float*)d_in[6],
                       (const float*)d_in[8], qkv);

    hipLaunchKernelGGL(attn_kernel, dim3(512), dim3(512), 0, stream,
                       qkv, qkv + XE, qkv + 2L * XE, ob);

    hipLaunchKernelGGL(out_kernel, dim3(256), dim3(256), 0, stream,
                       ob, wb + 3L * WE, (const float*)d_in[10], (float*)d_out);
}

// Round 36
// 126.347 us; speedup vs baseline: 1.0144x; 1.0120x over previous
//
#include <hip/hip_runtime.h>

// ---------------------------------------------------------------------------
// MultiHeadAttention forward, MI355X (gfx950).
// Weights-only fp32->bf16 convert; Q/K/V projections (128x128/BK=32 GEMM,
// TRIPLE-buffered single-barrier pipeline: buf = tile%3, stage(i+1) never
// aliases any buffer a skewed wave can read -> barrier2 deleted; A = fp32
// fused-convert T14 split with PWRITE at iter tail); flash attention v4b +
// XCD-chunked grid; output projection (proven dual-barrier core).
// ---------------------------------------------------------------------------

#define D_MODEL 1024
#define NHEADS  16
#define DKH     64
#define SEQ     2048
#define BATCH   2
#define MTOT    (BATCH * SEQ)            // 4096 rows
#define XE      ((long)MTOT * D_MODEL)   // 4194304 elems
#define WE      ((long)D_MODEL * D_MODEL)
#define QSCALE  0.18033688011112042f     // 0.125 * log2(e): softmax in exp2 domain

typedef __attribute__((ext_vector_type(8))) short short8v;   // 8 x bf16 (4 VGPR)
typedef __attribute__((ext_vector_type(4))) short short4v;   // 4 x bf16
typedef __attribute__((ext_vector_type(4))) float f32x4;     // MFMA C/D frag

typedef __attribute__((address_space(1))) void as1_void;
typedef __attribute__((address_space(3))) void as3_void;

__device__ __forceinline__ void gload16(const void* g, void* l) {
    __builtin_amdgcn_global_load_lds((const as1_void*)g, (as3_void*)l, 16, 0, 0);
}

__device__ __forceinline__ unsigned short f2bf(float x) {
    unsigned int u = __float_as_uint(x);
    u += 0x7FFFu + ((u >> 16) & 1u);     // RNE
    return (unsigned short)(u >> 16);
}

// native v_exp_f32: computes 2^x (avoid __exp2f: glibc name collision)
__device__ __forceinline__ float fexp2(float x) {
    return __builtin_amdgcn_exp2f(x);
}

// hardware packed f32x2 -> bf16x2 (RNE; one VALU op for two converts)
__device__ __forceinline__ unsigned int cvt_pk_bf16(float lo, float hi) {
    unsigned int r;
    asm("v_cvt_pk_bf16_f32 %0, %1, %2" : "=v"(r) : "v"(lo), "v"(hi));
    return r;
}

// XOR swizzle for [rows][64 bf16] LDS tiles (128B rows).
__device__ __forceinline__ int swz_u(int row, int col) {
    int byte = (col << 1) ^ ((row & 7) << 4);
    return (row << 6) + (byte >> 1);
}

// Vt swizzle: slot bits from (d&6)|((d>>3)&1): write pairs and reads stay 2-way.
__device__ __forceinline__ int swz_v(int d, int kv) {
    int slot = (d & 6) | ((d >> 3) & 1);
    int byte = (kv << 1) ^ (slot << 4);
    return (d << 6) + (byte >> 1);
}

// ---------------------------------------------------------------------------
// fp32 -> bf16 convert: WEIGHTS ONLY (Wq,Wk,Wv,Wo). blockIdx.y selects array.
// ---------------------------------------------------------------------------
struct ConvArgs {
    const float*    src[4];
    unsigned short* dst[4];
    int             n4[4];
};

__global__ __launch_bounds__(256) void convert_kernel(ConvArgs a) {
    int z = blockIdx.y;
    const float4*   s = (const float4*)a.src[z];
    unsigned short* d = a.dst[z];
    int n = a.n4[z];
    for (int i = blockIdx.x * blockDim.x + threadIdx.x; i < n;
         i += gridDim.x * blockDim.x) {
        float4 v = s[i];
        ushort4 o;
        o.x = f2bf(v.x); o.y = f2bf(v.y); o.z = f2bf(v.z); o.w = f2bf(v.w);
        *(ushort4*)(d + 4L * i) = o;
    }
}

// ---------------------------------------------------------------------------
// proj GEMM v7: 128x128 tile, BK=32, 4 waves, 256 threads, grid 768.
// TRIPLE-buffered (48 KB LDS, still 3 blocks/CU), ONE barrier per iter:
// iter i stages tile i+1 -> buf (i+1)%3, computes buf i%3. Max barrier skew
// is 1 iter, so a staging write targets a buffer last read 2 barriers ago —
// never aliased. PWRITE_A at iter tail (r31's cost is repaid by deleting
// barrier2). vmcnt(6) completes exactly B(cur) (outstanding = B(cur) 2 +
// A(nxt) 4 + B(nxt) 2). lgkmcnt(0) before barrier publishes own A-writes.
// ---------------------------------------------------------------------------
__global__ __launch_bounds__(256) void proj_kernel(
    const float* __restrict__ xq, const float* __restrict__ xk,
    const float* __restrict__ xv, const unsigned short* __restrict__ wb,
    const float* __restrict__ bq, const float* __restrict__ bk,
    const float* __restrict__ bv, unsigned short* __restrict__ qkv) {
    __shared__ unsigned short As[3 * 128 * 32];   // 24 KB
    __shared__ unsigned short Bs[3 * 128 * 32];   // 24 KB

    const int t    = threadIdx.x;
    const int lane = t & 63;
    const int w    = t >> 6;
    const int wm   = w >> 1, wn = w & 1;
    const int l15  = lane & 15, g = lane >> 4;

    // XCD-chunked decode: 768 blocks; xcd owns M-tiles 4*xcd..4*xcd+3
    const int bid = blockIdx.x;
    const int xcd = bid & 7;
    const int k   = bid >> 3;            // 0..95 = 4(y) x 8(x) x 3(z)
    const int ty  = (xcd << 2) | (k & 3);
    const int tx  = (k >> 2) & 7;
    const int z   = k >> 5;
    const float* bias = (z == 0) ? bq : (z == 1) ? bk : bv;
    const float scale = (z == 0) ? QSCALE : 1.0f;

    const float* Af = (z == 0) ? xq : (z == 1) ? xk : xv;   // fp32 source
    const unsigned short* Bm = wb + (long)z * WE;
    unsigned short*       C  = qkv + (long)z * XE;
    const long m0 = (long)ty * 128;
    const long n0 = (long)tx * 128;
    const int  K  = D_MODEL;

    f32x4 acc[4][4] = {};

    // staging geometry: per matrix 512 16B-bf16-chunks; 2 per thread.
    const int idx0 = t, idx1 = t + 256;
    const int r0 = idx0 >> 2, c0 = (idx0 & 3) * 8;
    const int r1 = idx1 >> 2, c1 = (idx1 & 3) * 8;

    float4 a0_[2], a1_[2];   // in-flight fp32 A regs (issue-early)

#define PLOAD_A(k0)                                                        \
    {                                                                      \
        const float* s0 = Af + (m0 + r0) * K + (k0) + c0;                  \
        const float* s1 = Af + (m0 + r1) * K + (k0) + c1;                  \
        a0_[0] = *(const float4*)(s0);                                     \
        a1_[0] = *(const float4*)(s0 + 4);                                 \
        a0_[1] = *(const float4*)(s1);                                     \
        a1_[1] = *(const float4*)(s1 + 4);                                 \
    }

#define PSTAGE_B(k0, buf)                                                  \
    gload16(Bm + (n0 + r0) * K + (k0) + c0, &Bs[(buf) * 4096 + idx0 * 8]); \
    gload16(Bm + (n0 + r1) * K + (k0) + c1, &Bs[(buf) * 4096 + idx1 * 8]);

#define PWRITE_A(buf)                                                      \
    {                                                                      \
        uint4 pk;                                                          \
        pk.x = cvt_pk_bf16(a0_[0].x, a0_[0].y);                            \
        pk.y = cvt_pk_bf16(a0_[0].z, a0_[0].w);                            \
        pk.z = cvt_pk_bf16(a1_[0].x, a1_[0].y);                            \
        pk.w = cvt_pk_bf16(a1_[0].z, a1_[0].w);                            \
        *(uint4*)&As[(buf) * 4096 + idx0 * 8] = pk;                        \
        pk.x = cvt_pk_bf16(a0_[1].x, a0_[1].y);                            \
        pk.y = cvt_pk_bf16(a0_[1].z, a0_[1].w);                            \
        pk.z = cvt_pk_bf16(a1_[1].x, a1_[1].y);                            \
        pk.w = cvt_pk_bf16(a1_[1].z, a1_[1].w);                            \
        *(uint4*)&As[(buf) * 4096 + idx1 * 8] = pk;                        \
    }

    // ---- prologue: stage tile 0 into buffer 0 ----
    PLOAD_A(0);
    PSTAGE_B(0, 0);
    PWRITE_A(0);             // compiler waits the A regs; B stays in flight
    int cur = 0;

    for (int it = 0; it < K / 32; ++it) {           // 32 iters, ONE barrier each
        const int nxt = (cur == 2) ? 0 : cur + 1;
        const int kn  = ((it + 1) * 32) & (K - 1);  // wrapped prefetch
        PLOAD_A(kn);         // A(nxt) -> regs, in flight across compute
        PSTAGE_B(kn, nxt);
        // outstanding: B(cur) 2 + A(nxt) 4 + B(nxt) 2 = 8; finish B(cur)
        asm volatile("s_waitcnt vmcnt(6)" ::: "memory");
        asm volatile("s_waitcnt lgkmcnt(0)" ::: "memory"); // own A-writes drained
        __builtin_amdgcn_sched_barrier(0);
        __builtin_amdgcn_s_barrier();
        __builtin_amdgcn_sched_barrier(0);

        const unsigned short* Ab = &As[cur * 4096];
        const unsigned short* Bb = &Bs[cur * 4096];

        short8v af[4], bf_[4];
#pragma unroll
        for (int mf = 0; mf < 4; ++mf)
            af[mf] = *(const short8v*)&Ab[(wm * 64 + mf * 16 + l15) * 32 + g * 8];
#pragma unroll
        for (int nf = 0; nf < 4; ++nf)
            bf_[nf] = *(const short8v*)&Bb[(wn * 64 + nf * 16 + l15) * 32 + g * 8];
        __builtin_amdgcn_s_setprio(1);
#pragma unroll
        for (int mf = 0; mf < 4; ++mf)
#pragma unroll
            for (int nf = 0; nf < 4; ++nf)
                acc[mf][nf] = __builtin_amdgcn_mfma_f32_16x16x32_bf16(
                    af[mf], bf_[nf], acc[mf][nf], 0, 0, 0);
        __builtin_amdgcn_s_setprio(0);

        // ---- iter tail: write A(nxt) into buf nxt. Any wave reading LDS is
        //      in compute of THIS iter (buf cur) or at most the previous one
        //      (buf prev = nxt-2 mod 3); both disjoint from nxt. ----
        PWRITE_A(nxt);
        cur = nxt;
    }

    // ---- epilogue: bias + scale, bf16 write ----
    float bvv[4];
#pragma unroll
    for (int nf = 0; nf < 4; ++nf)
        bvv[nf] = bias[n0 + wn * 64 + nf * 16 + l15];

#pragma unroll
    for (int mf = 0; mf < 4; ++mf)
#pragma unroll
        for (int nf = 0; nf < 4; ++nf)
#pragma unroll
            for (int r = 0; r < 4; ++r) {
                long row = m0 + wm * 64 + mf * 16 + g * 4 + r;
                long col = n0 + wn * 64 + nf * 16 + l15;
                C[row * (long)D_MODEL + col] =
                    f2bf((acc[mf][nf][r] + bvv[nf]) * scale);
            }
#undef PLOAD_A
#undef PSTAGE_B
#undef PWRITE_A
}

// ---------------------------------------------------------------------------
// out GEMM: proven 128x128/BK=32 core, XCD-chunked, 256 blocks.
// ---------------------------------------------------------------------------
__global__ __launch_bounds__(256) void out_kernel(
    const unsigned short* __restrict__ ob, const unsigned short* __restrict__ wo,
    const float* __restrict__ bo, float* __restrict__ out) {
    __shared__ unsigned short As[128 * 32];
    __shared__ unsigned short Bs[128 * 32];

    const int t    = threadIdx.x;
    const int lane = t & 63;
    const int w    = t >> 6;
    const int wm   = w >> 1, wn = w & 1;
    const int l15  = lane & 15, g = lane >> 4;

    const int bid = blockIdx.x;
    const int xcd = bid & 7;
    const int k   = bid >> 3;            // 0..31 = 4(y) x 8(x)
    const long m0 = (long)((xcd << 2) | (k & 3)) * 128;
    const long n0 = (long)(k >> 2) * 128;
    const int  K  = D_MODEL, N = D_MODEL;

    f32x4 acc[4][4] = {};

    const int idx0 = t, idx1 = t + 256;
    const int r0 = idx0 >> 2, c0 = (idx0 & 3) * 8;
    const int r1 = idx1 >> 2, c1 = (idx1 & 3) * 8;
    const unsigned short* pa0 = ob + (m0 + r0) * K + c0;
    const unsigned short* pa1 = ob + (m0 + r1) * K + c1;
    const unsigned short* pb0 = wo + (n0 + r0) * K + c0;
    const unsigned short* pb1 = wo + (n0 + r1) * K + c1;

    for (int k0 = 0; k0 < K; k0 += 32) {
        gload16(pa0 + k0, &As[idx0 * 8]);
        gload16(pa1 + k0, &As[idx1 * 8]);
        gload16(pb0 + k0, &Bs[idx0 * 8]);
        gload16(pb1 + k0, &Bs[idx1 * 8]);
        __syncthreads();

        short8v af[4], bf_[4];
#pragma unroll
        for (int mf = 0; mf < 4; ++mf)
            af[mf] = *(const short8v*)&As[(wm * 64 + mf * 16 + l15) * 32 + g * 8];
#pragma unroll
        for (int nf = 0; nf < 4; ++nf)
            bf_[nf] = *(const short8v*)&Bs[(wn * 64 + nf * 16 + l15) * 32 + g * 8];
#pragma unroll
        for (int mf = 0; mf < 4; ++mf)
#pragma unroll
            for (int nf = 0; nf < 4; ++nf)
                acc[mf][nf] = __builtin_amdgcn_mfma_f32_16x16x32_bf16(
                    af[mf], bf_[nf], acc[mf][nf], 0, 0, 0);
        __syncthreads();
    }

    float bvv[4];
#pragma unroll
    for (int nf = 0; nf < 4; ++nf)
        bvv[nf] = bo[n0 + wn * 64 + nf * 16 + l15];

#pragma unroll
    for (int mf = 0; mf < 4; ++mf)
#pragma unroll
        for (int nf = 0; nf < 4; ++nf)
#pragma unroll
            for (int r = 0; r < 4; ++r) {
                long row = m0 + wm * 64 + mf * 16 + g * 4 + r;
                long col = n0 + wn * 64 + nf * 16 + l15;
                out[row * (long)N + col] = acc[mf][nf][r] + bvv[nf];
            }
}

// ---------------------------------------------------------------------------
// Flash attention v4b + XCD-chunked grid (measured 63.0-63.8 us).
// ---------------------------------------------------------------------------
#define KVB 4096   // elems per K/V buffer (64 rows x 64)

__global__ __launch_bounds__(512) void attn_kernel(
    const unsigned short* __restrict__ Qb, const unsigned short* __restrict__ Kb,
    const unsigned short* __restrict__ Vb, unsigned short* __restrict__ Ob) {
    __shared__ alignas(16) unsigned short Ks[2 * KVB];     // 16 KB
    __shared__ alignas(16) unsigned short Vt[2 * KVB];     // 16 KB  V^T [d][kv]
    __shared__ alignas(16) unsigned short Ps[8][16 * 64];  // 16 KB  per-wave P
    __shared__ alignas(16) float corrS[8][16];

    const int t = threadIdx.x, lane = t & 63, w = t >> 6;
    const int l15 = lane & 15, g = lane >> 4;
    const int bid = blockIdx.x;
    const int xcd = bid & 7;
    const int kk2 = bid >> 3;              // 0..63
    const int bh  = (xcd << 2) | (kk2 & 3);
    const int qb  = kk2 >> 2;              // 0..15
    const long headoff = (long)(bh >> 4) * SEQ * D_MODEL + (long)(bh & 15) * DKH;
    const int q0w = qb * 128 + w * 16;

    short8v qf[2];
#pragma unroll
    for (int ks = 0; ks < 2; ++ks)
        qf[ks] = *(const short8v*)(Qb + headoff +
            (long)(q0w + l15) * D_MODEL + ks * 32 + g * 8);

    short8v onesv;
#pragma unroll
    for (int j = 0; j < 8; ++j) onesv[j] = (short)0x3F80;

    f32x4 o[4] = {};
    f32x4 ol = {};
    float mrun = -3.0e38f;

    const int vd0  = (t & 31) * 2;
    const int vkv0 = (t >> 5) * 4;
    const int kr0 = t >> 3, ks0 = t & 7;

    unsigned int va[4];

#define ISSUE_V(kt)                                                        \
    _Pragma("unroll")                                                      \
    for (int j = 0; j < 4; ++j)                                            \
        va[j] = *(const unsigned int*)(Vb + headoff +                      \
            (long)((kt) + vkv0 + j) * D_MODEL + vd0);

#define ISSUE_K(kt, off)                                                   \
    gload16(Kb + headoff + (long)((kt) + kr0) * D_MODEL +                  \
                ((ks0 ^ (kr0 & 7)) << 3), &Ks[(off) + t * 8]);

#define WRITE_V(off)                                                       \
    {                                                                      \
        short4v ra, rb;                                                    \
        _Pragma("unroll")                                                  \
        for (int j = 0; j < 4; ++j) {                                      \
            ra[j] = (short)(va[j] & 0xffffu);                              \
            rb[j] = (short)(va[j] >> 16);                                  \
        }                                                                  \
        *(short4v*)&Vt[(off) + swz_v(vd0,     vkv0)] = ra;                 \
        *(short4v*)&Vt[(off) + swz_v(vd0 + 1, vkv0)] = rb;                 \
    }

    asm volatile("s_waitcnt vmcnt(0)" ::: "memory");
    ISSUE_V(0);
    ISSUE_K(0, 0);
    WRITE_V(0);
    int cur = 0;

    for (int it = 0; it < SEQ / 64; ++it) {
        const int nxt = cur ^ 1;
        const int ktn = (((it + 1) & (SEQ / 64 - 1))) * 64;
        ISSUE_V(ktn);
        ISSUE_K(ktn, nxt * KVB);
        asm volatile("s_waitcnt vmcnt(5)" ::: "memory");
        asm volatile("s_waitcnt lgkmcnt(0)" ::: "memory");
        __builtin_amdgcn_sched_barrier(0);
        __builtin_amdgcn_s_barrier();
        __builtin_amdgcn_sched_barrier(0);

        const int kO = cur * KVB;

        f32x4 st[4] = {};
        __builtin_amdgcn_s_setprio(1);
#pragma unroll
        for (int ks = 0; ks < 2; ++ks)
#pragma unroll
            for (int mf = 0; mf < 4; ++mf) {
                short8v kf = *(const short8v*)&Ks[kO + swz_u(mf * 16 + l15, ks * 32 + g * 8)];
                st[mf] = __builtin_amdgcn_mfma_f32_16x16x32_bf16(
                    kf, qf[ks], st[mf], 0, 0, 0);
            }
        __builtin_amdgcn_s_setprio(0);

        float vmax = st[0][0];
#pragma unroll
        for (int mf = 0; mf < 4; ++mf)
#pragma unroll
            for (int r = 0; r < 4; ++r)
                vmax = fmaxf(vmax, st[mf][r]);
        vmax = fmaxf(vmax, __shfl_xor(vmax, 16));
        vmax = fmaxf(vmax, __shfl_xor(vmax, 32));

        const bool grow = __any(vmax > mrun + 8.0f);
        if (grow) {
            float mnew = fmaxf(mrun, vmax);
            float corr = fexp2(mrun - mnew);
            mrun = mnew;
            if (g == 0) corrS[w][l15] = corr;
        }

#pragma unroll
        for (int mf = 0; mf < 4; ++mf)
#pragma unroll
            for (int r = 0; r < 4; ++r)
                st[mf][r] = fexp2(st[mf][r] - mrun);

        unsigned short* Pw = Ps[w];
#pragma unroll
        for (int mf = 0; mf < 4; ++mf) {
            uint2 pk;
            pk.x = cvt_pk_bf16(st[mf][0], st[mf][1]);
            pk.y = cvt_pk_bf16(st[mf][2], st[mf][3]);
            *(uint2*)&Pw[swz_u(l15, mf * 16 + g * 4)] = pk;
        }

        if (grow) {
            float4 cv = *(const float4*)&corrS[w][g * 4];
#pragma unroll
            for (int nd = 0; nd < 4; ++nd)
#pragma unroll
                for (int r = 0; r < 4; ++r)
                    o[nd][r] *= cv[r];
#pragma unroll
            for (int r = 0; r < 4; ++r) ol[r] *= cv[r];
        }

        __builtin_amdgcn_s_setprio(1);
#pragma unroll
        for (int ks2 = 0; ks2 < 2; ++ks2) {
            short8v pf = *(const short8v*)&Pw[swz_u(l15, ks2 * 32 + g * 8)];
            ol = __builtin_amdgcn_mfma_f32_16x16x32_bf16(
                pf, onesv, ol, 0, 0, 0);
#pragma unroll
            for (int nd = 0; nd < 4; ++nd) {
                short8v vf = *(const short8v*)&Vt[kO + swz_v(nd * 16 + l15, ks2 * 32 + g * 8)];
                o[nd] = __builtin_amdgcn_mfma_f32_16x16x32_bf16(
                    pf, vf, o[nd], 0, 0, 0);
            }
        }
        __builtin_amdgcn_s_setprio(0);

        WRITE_V(nxt * KVB);
        cur = nxt;
    }

#pragma unroll
    for (int r = 0; r < 4; ++r) {
        float inv = 1.f / (ol[r] + 1e-9f);
        long rowoff = headoff + (long)(q0w + g * 4 + r) * D_MODEL;
#pragma unroll
        for (int nd = 0; nd < 4; ++nd)
            Ob[rowoff + nd * 16 + l15] = f2bf(o[nd][r] * inv);
    }
#undef ISSUE_V
#undef ISSUE_K
#undef WRITE_V
}

// ---------------------------------------------------------------------------
// Launch
// ---------------------------------------------------------------------------
extern "C" void kernel_launch(void* const* d_in, const int* in_sizes, int n_in,
                              void* d_out, int out_size, void* d_ws, size_t ws_size,
                              hipStream_t stream) {
    // d_in order: 0 q, 1 k, 2 v, 3 Wq, 4 bq, 5 Wk, 6 bk, 7 Wv, 8 bv, 9 Wo, 10 bo
    unsigned short* ws  = (unsigned short*)d_ws;
    unsigned short* wb  = ws;                       // 4*WE  bf16 weights
    unsigned short* qkv = ws + 4L * WE;             // 3*XE  Q(scaled), K, V
    unsigned short* ob  = qkv + 3L * XE;            // XE    attention output

    ConvArgs ca;
    ca.src[0] = (const float*)d_in[3]; ca.dst[0] = wb;           ca.n4[0] = (int)(WE / 4);
    ca.src[1] = (const float*)d_in[5]; ca.dst[1] = wb + WE;      ca.n4[1] = (int)(WE / 4);
    ca.src[2] = (const float*)d_in[7]; ca.dst[2] = wb + 2L * WE; ca.n4[2] = (int)(WE / 4);
    ca.src[3] = (const float*)d_in[9]; ca.dst[3] = wb + 3L * WE; ca.n4[3] = (int)(WE / 4);

    hipLaunchKernelGGL(convert_kernel, dim3(512, 4), dim3(256), 0, stream, ca);

    hipLaunchKernelGGL(proj_kernel, dim3(768), dim3(256), 0, stream,
                       (const float*)d_in[0], (const float*)d_in[1],
                       (const float*)d_in[2], wb,
                       (const float*)d_in[4], (const float*)d_in[6],
                       (const float*)d_in[8], qkv);

    hipLaunchKernelGGL(attn_kernel, dim3(512), dim3(512), 0, stream,
                       qkv, qkv + XE, qkv + 2L * XE, ob);

    hipLaunchKernelGGL(out_kernel, dim3(256), dim3(256), 0, stream,
                       ob, wb + 3L * WE, (const float*)d_in[10], (float*)d_out);
}

// Round 37
// 123.364 us; speedup vs baseline: 1.0389x; 1.0242x over previous
//
#include <hip/hip_runtime.h>

// ---------------------------------------------------------------------------
// MultiHeadAttention forward, MI355X (gfx950).
// Weights-only fp32->bf16 convert; Q/K/V projections (128x128/BK=32,
// TRIPLE-buffered single-barrier, fused A-convert T14); flash attention v4b
// + XCD-chunked grid; output projection NOW ALSO tri-buffered single-barrier
// with counted vmcnt(4) (was dual-syncthreads vmcnt(0) drain).
// ---------------------------------------------------------------------------

#define D_MODEL 1024
#define NHEADS  16
#define DKH     64
#define SEQ     2048
#define BATCH   2
#define MTOT    (BATCH * SEQ)            // 4096 rows
#define XE      ((long)MTOT * D_MODEL)   // 4194304 elems
#define WE      ((long)D_MODEL * D_MODEL)
#define QSCALE  0.18033688011112042f     // 0.125 * log2(e): softmax in exp2 domain

typedef __attribute__((ext_vector_type(8))) short short8v;   // 8 x bf16 (4 VGPR)
typedef __attribute__((ext_vector_type(4))) short short4v;   // 4 x bf16
typedef __attribute__((ext_vector_type(4))) float f32x4;     // MFMA C/D frag

typedef __attribute__((address_space(1))) void as1_void;
typedef __attribute__((address_space(3))) void as3_void;

__device__ __forceinline__ void gload16(const void* g, void* l) {
    __builtin_amdgcn_global_load_lds((const as1_void*)g, (as3_void*)l, 16, 0, 0);
}

__device__ __forceinline__ unsigned short f2bf(float x) {
    unsigned int u = __float_as_uint(x);
    u += 0x7FFFu + ((u >> 16) & 1u);     // RNE
    return (unsigned short)(u >> 16);
}

// native v_exp_f32: computes 2^x (avoid __exp2f: glibc name collision)
__device__ __forceinline__ float fexp2(float x) {
    return __builtin_amdgcn_exp2f(x);
}

// hardware packed f32x2 -> bf16x2 (RNE; one VALU op for two converts)
__device__ __forceinline__ unsigned int cvt_pk_bf16(float lo, float hi) {
    unsigned int r;
    asm("v_cvt_pk_bf16_f32 %0, %1, %2" : "=v"(r) : "v"(lo), "v"(hi));
    return r;
}

// XOR swizzle for [rows][64 bf16] LDS tiles (128B rows).
__device__ __forceinline__ int swz_u(int row, int col) {
    int byte = (col << 1) ^ ((row & 7) << 4);
    return (row << 6) + (byte >> 1);
}

// Vt swizzle: slot bits from (d&6)|((d>>3)&1): write pairs and reads stay 2-way.
__device__ __forceinline__ int swz_v(int d, int kv) {
    int slot = (d & 6) | ((d >> 3) & 1);
    int byte = (kv << 1) ^ (slot << 4);
    return (d << 6) + (byte >> 1);
}

// ---------------------------------------------------------------------------
// fp32 -> bf16 convert: WEIGHTS ONLY (Wq,Wk,Wv,Wo). blockIdx.y selects array.
// ---------------------------------------------------------------------------
struct ConvArgs {
    const float*    src[4];
    unsigned short* dst[4];
    int             n4[4];
};

__global__ __launch_bounds__(256) void convert_kernel(ConvArgs a) {
    int z = blockIdx.y;
    const float4*   s = (const float4*)a.src[z];
    unsigned short* d = a.dst[z];
    int n = a.n4[z];
    for (int i = blockIdx.x * blockDim.x + threadIdx.x; i < n;
         i += gridDim.x * blockDim.x) {
        float4 v = s[i];
        ushort4 o;
        o.x = f2bf(v.x); o.y = f2bf(v.y); o.z = f2bf(v.z); o.w = f2bf(v.w);
        *(ushort4*)(d + 4L * i) = o;
    }
}

// ---------------------------------------------------------------------------
// proj GEMM v7 (round-36 best): 128x128 tile, BK=32, 4 waves, 256 threads,
// grid 768. TRIPLE-buffered (48 KB LDS, 3 blocks/CU), ONE barrier per iter.
// A = fp32 fused-convert T14 split, PWRITE_A at iter tail (safe: targets a
// buffer last read 2 barriers ago). vmcnt(6) completes exactly B(cur).
// ---------------------------------------------------------------------------
__global__ __launch_bounds__(256) void proj_kernel(
    const float* __restrict__ xq, const float* __restrict__ xk,
    const float* __restrict__ xv, const unsigned short* __restrict__ wb,
    const float* __restrict__ bq, const float* __restrict__ bk,
    const float* __restrict__ bv, unsigned short* __restrict__ qkv) {
    __shared__ unsigned short As[3 * 128 * 32];   // 24 KB
    __shared__ unsigned short Bs[3 * 128 * 32];   // 24 KB

    const int t    = threadIdx.x;
    const int lane = t & 63;
    const int w    = t >> 6;
    const int wm   = w >> 1, wn = w & 1;
    const int l15  = lane & 15, g = lane >> 4;

    // XCD-chunked decode: 768 blocks; xcd owns M-tiles 4*xcd..4*xcd+3
    const int bid = blockIdx.x;
    const int xcd = bid & 7;
    const int k   = bid >> 3;            // 0..95 = 4(y) x 8(x) x 3(z)
    const int ty  = (xcd << 2) | (k & 3);
    const int tx  = (k >> 2) & 7;
    const int z   = k >> 5;
    const float* bias = (z == 0) ? bq : (z == 1) ? bk : bv;
    const float scale = (z == 0) ? QSCALE : 1.0f;

    const float* Af = (z == 0) ? xq : (z == 1) ? xk : xv;   // fp32 source
    const unsigned short* Bm = wb + (long)z * WE;
    unsigned short*       C  = qkv + (long)z * XE;
    const long m0 = (long)ty * 128;
    const long n0 = (long)tx * 128;
    const int  K  = D_MODEL;

    f32x4 acc[4][4] = {};

    // staging geometry: per matrix 512 16B-bf16-chunks; 2 per thread.
    const int idx0 = t, idx1 = t + 256;
    const int r0 = idx0 >> 2, c0 = (idx0 & 3) * 8;
    const int r1 = idx1 >> 2, c1 = (idx1 & 3) * 8;

    float4 a0_[2], a1_[2];   // in-flight fp32 A regs (issue-early)

#define PLOAD_A(k0)                                                        \
    {                                                                      \
        const float* s0 = Af + (m0 + r0) * K + (k0) + c0;                  \
        const float* s1 = Af + (m0 + r1) * K + (k0) + c1;                  \
        a0_[0] = *(const float4*)(s0);                                     \
        a1_[0] = *(const float4*)(s0 + 4);                                 \
        a0_[1] = *(const float4*)(s1);                                     \
        a1_[1] = *(const float4*)(s1 + 4);                                 \
    }

#define PSTAGE_B(k0, buf)                                                  \
    gload16(Bm + (n0 + r0) * K + (k0) + c0, &Bs[(buf) * 4096 + idx0 * 8]); \
    gload16(Bm + (n0 + r1) * K + (k0) + c1, &Bs[(buf) * 4096 + idx1 * 8]);

#define PWRITE_A(buf)                                                      \
    {                                                                      \
        uint4 pk;                                                          \
        pk.x = cvt_pk_bf16(a0_[0].x, a0_[0].y);                            \
        pk.y = cvt_pk_bf16(a0_[0].z, a0_[0].w);                            \
        pk.z = cvt_pk_bf16(a1_[0].x, a1_[0].y);                            \
        pk.w = cvt_pk_bf16(a1_[0].z, a1_[0].w);                            \
        *(uint4*)&As[(buf) * 4096 + idx0 * 8] = pk;                        \
        pk.x = cvt_pk_bf16(a0_[1].x, a0_[1].y);                            \
        pk.y = cvt_pk_bf16(a0_[1].z, a0_[1].w);                            \
        pk.z = cvt_pk_bf16(a1_[1].x, a1_[1].y);                            \
        pk.w = cvt_pk_bf16(a1_[1].z, a1_[1].w);                            \
        *(uint4*)&As[(buf) * 4096 + idx1 * 8] = pk;                        \
    }

    // ---- prologue: stage tile 0 into buffer 0 ----
    PLOAD_A(0);
    PSTAGE_B(0, 0);
    PWRITE_A(0);             // compiler waits the A regs; B stays in flight
    int cur = 0;

    for (int it = 0; it < K / 32; ++it) {           // 32 iters, ONE barrier each
        const int nxt = (cur == 2) ? 0 : cur + 1;
        const int kn  = ((it + 1) * 32) & (K - 1);  // wrapped prefetch
        PLOAD_A(kn);         // A(nxt) -> regs, in flight across compute
        PSTAGE_B(kn, nxt);
        // outstanding: B(cur) 2 + A(nxt) 4 + B(nxt) 2 = 8; finish B(cur)
        asm volatile("s_waitcnt vmcnt(6)" ::: "memory");
        asm volatile("s_waitcnt lgkmcnt(0)" ::: "memory"); // own A-writes drained
        __builtin_amdgcn_sched_barrier(0);
        __builtin_amdgcn_s_barrier();
        __builtin_amdgcn_sched_barrier(0);

        const unsigned short* Ab = &As[cur * 4096];
        const unsigned short* Bb = &Bs[cur * 4096];

        short8v af[4], bf_[4];
#pragma unroll
        for (int mf = 0; mf < 4; ++mf)
            af[mf] = *(const short8v*)&Ab[(wm * 64 + mf * 16 + l15) * 32 + g * 8];
#pragma unroll
        for (int nf = 0; nf < 4; ++nf)
            bf_[nf] = *(const short8v*)&Bb[(wn * 64 + nf * 16 + l15) * 32 + g * 8];
        __builtin_amdgcn_s_setprio(1);
#pragma unroll
        for (int mf = 0; mf < 4; ++mf)
#pragma unroll
            for (int nf = 0; nf < 4; ++nf)
                acc[mf][nf] = __builtin_amdgcn_mfma_f32_16x16x32_bf16(
                    af[mf], bf_[nf], acc[mf][nf], 0, 0, 0);
        __builtin_amdgcn_s_setprio(0);

        // ---- iter tail: write A(nxt) into buf nxt (disjoint, see header) ----
        PWRITE_A(nxt);
        cur = nxt;
    }

    // ---- epilogue: bias + scale, bf16 write ----
    float bvv[4];
#pragma unroll
    for (int nf = 0; nf < 4; ++nf)
        bvv[nf] = bias[n0 + wn * 64 + nf * 16 + l15];

#pragma unroll
    for (int mf = 0; mf < 4; ++mf)
#pragma unroll
        for (int nf = 0; nf < 4; ++nf)
#pragma unroll
            for (int r = 0; r < 4; ++r) {
                long row = m0 + wm * 64 + mf * 16 + g * 4 + r;
                long col = n0 + wn * 64 + nf * 16 + l15;
                C[row * (long)D_MODEL + col] =
                    f2bf((acc[mf][nf][r] + bvv[nf]) * scale);
            }
#undef PLOAD_A
#undef PSTAGE_B
#undef PWRITE_A
}

// ---------------------------------------------------------------------------
// out GEMM v3: 128x128/BK=32, TRIPLE-buffered single-barrier (same proven
// structure as proj v7): stage tile i+1 -> buf (i+1)%3, compute buf i%3,
// one barrier with counted vmcnt(4) (outstanding = cur 4 + nxt 4 = 8;
// completes exactly cur's gloads). 48+48 KB LDS irrelevant at 1 block/CU.
// XCD-chunked, 256 blocks.
// ---------------------------------------------------------------------------
__global__ __launch_bounds__(256) void out_kernel(
    const unsigned short* __restrict__ ob, const unsigned short* __restrict__ wo,
    const float* __restrict__ bo, float* __restrict__ out) {
    __shared__ unsigned short As[3 * 128 * 32];   // 24 KB
    __shared__ unsigned short Bs[3 * 128 * 32];   // 24 KB

    const int t    = threadIdx.x;
    const int lane = t & 63;
    const int w    = t >> 6;
    const int wm   = w >> 1, wn = w & 1;
    const int l15  = lane & 15, g = lane >> 4;

    const int bid = blockIdx.x;
    const int xcd = bid & 7;
    const int k   = bid >> 3;            // 0..31 = 4(y) x 8(x)
    const long m0 = (long)((xcd << 2) | (k & 3)) * 128;
    const long n0 = (long)(k >> 2) * 128;
    const int  K  = D_MODEL, N = D_MODEL;

    f32x4 acc[4][4] = {};

    const int idx0 = t, idx1 = t + 256;
    const int r0 = idx0 >> 2, c0 = (idx0 & 3) * 8;
    const int r1 = idx1 >> 2, c1 = (idx1 & 3) * 8;
    const unsigned short* pa0 = ob + (m0 + r0) * K + c0;
    const unsigned short* pa1 = ob + (m0 + r1) * K + c1;
    const unsigned short* pb0 = wo + (n0 + r0) * K + c0;
    const unsigned short* pb1 = wo + (n0 + r1) * K + c1;

#define OSTAGE(k0, buf)                                                    \
    gload16(pa0 + (k0), &As[(buf) * 4096 + idx0 * 8]);                     \
    gload16(pa1 + (k0), &As[(buf) * 4096 + idx1 * 8]);                     \
    gload16(pb0 + (k0), &Bs[(buf) * 4096 + idx0 * 8]);                     \
    gload16(pb1 + (k0), &Bs[(buf) * 4096 + idx1 * 8]);

    // ---- prologue: stage tile 0 into buffer 0 ----
    OSTAGE(0, 0);
    int cur = 0;

    for (int it = 0; it < K / 32; ++it) {           // 32 iters, ONE barrier each
        const int nxt = (cur == 2) ? 0 : cur + 1;
        const int kn  = ((it + 1) * 32) & (K - 1);  // wrapped prefetch
        OSTAGE(kn, nxt);     // targets buf last read 2 barriers ago (safe)
        // outstanding: cur 4 + nxt 4 = 8; finish cur's gloads only
        asm volatile("s_waitcnt vmcnt(4)" ::: "memory");
        __builtin_amdgcn_sched_barrier(0);
        __builtin_amdgcn_s_barrier();
        __builtin_amdgcn_sched_barrier(0);

        const unsigned short* Ab = &As[cur * 4096];
        const unsigned short* Bb = &Bs[cur * 4096];

        short8v af[4], bf_[4];
#pragma unroll
        for (int mf = 0; mf < 4; ++mf)
            af[mf] = *(const short8v*)&Ab[(wm * 64 + mf * 16 + l15) * 32 + g * 8];
#pragma unroll
        for (int nf = 0; nf < 4; ++nf)
            bf_[nf] = *(const short8v*)&Bb[(wn * 64 + nf * 16 + l15) * 32 + g * 8];
        __builtin_amdgcn_s_setprio(1);
#pragma unroll
        for (int mf = 0; mf < 4; ++mf)
#pragma unroll
            for (int nf = 0; nf < 4; ++nf)
                acc[mf][nf] = __builtin_amdgcn_mfma_f32_16x16x32_bf16(
                    af[mf], bf_[nf], acc[mf][nf], 0, 0, 0);
        __builtin_amdgcn_s_setprio(0);
        cur = nxt;
    }

    float bvv[4];
#pragma unroll
    for (int nf = 0; nf < 4; ++nf)
        bvv[nf] = bo[n0 + wn * 64 + nf * 16 + l15];

#pragma unroll
    for (int mf = 0; mf < 4; ++mf)
#pragma unroll
        for (int nf = 0; nf < 4; ++nf)
#pragma unroll
            for (int r = 0; r < 4; ++r) {
                long row = m0 + wm * 64 + mf * 16 + g * 4 + r;
                long col = n0 + wn * 64 + nf * 16 + l15;
                out[row * (long)N + col] = acc[mf][nf][r] + bvv[nf];
            }
#undef OSTAGE
}

// ---------------------------------------------------------------------------
// Flash attention v4b + XCD-chunked grid (measured 63.0-63.8 us).
// ---------------------------------------------------------------------------
#define KVB 4096   // elems per K/V buffer (64 rows x 64)

__global__ __launch_bounds__(512) void attn_kernel(
    const unsigned short* __restrict__ Qb, const unsigned short* __restrict__ Kb,
    const unsigned short* __restrict__ Vb, unsigned short* __restrict__ Ob) {
    __shared__ alignas(16) unsigned short Ks[2 * KVB];     // 16 KB
    __shared__ alignas(16) unsigned short Vt[2 * KVB];     // 16 KB  V^T [d][kv]
    __shared__ alignas(16) unsigned short Ps[8][16 * 64];  // 16 KB  per-wave P
    __shared__ alignas(16) float corrS[8][16];

    const int t = threadIdx.x, lane = t & 63, w = t >> 6;
    const int l15 = lane & 15, g = lane >> 4;
    const int bid = blockIdx.x;
    const int xcd = bid & 7;
    const int kk2 = bid >> 3;              // 0..63
    const int bh  = (xcd << 2) | (kk2 & 3);
    const int qb  = kk2 >> 2;              // 0..15
    const long headoff = (long)(bh >> 4) * SEQ * D_MODEL + (long)(bh & 15) * DKH;
    const int q0w = qb * 128 + w * 16;

    short8v qf[2];
#pragma unroll
    for (int ks = 0; ks < 2; ++ks)
        qf[ks] = *(const short8v*)(Qb + headoff +
            (long)(q0w + l15) * D_MODEL + ks * 32 + g * 8);

    short8v onesv;
#pragma unroll
    for (int j = 0; j < 8; ++j) onesv[j] = (short)0x3F80;

    f32x4 o[4] = {};
    f32x4 ol = {};
    float mrun = -3.0e38f;

    const int vd0  = (t & 31) * 2;
    const int vkv0 = (t >> 5) * 4;
    const int kr0 = t >> 3, ks0 = t & 7;

    unsigned int va[4];

#define ISSUE_V(kt)                                                        \
    _Pragma("unroll")                                                      \
    for (int j = 0; j < 4; ++j)                                            \
        va[j] = *(const unsigned int*)(Vb + headoff +                      \
            (long)((kt) + vkv0 + j) * D_MODEL + vd0);

#define ISSUE_K(kt, off)                                                   \
    gload16(Kb + headoff + (long)((kt) + kr0) * D_MODEL +                  \
                ((ks0 ^ (kr0 & 7)) << 3), &Ks[(off) + t * 8]);

#define WRITE_V(off)                                                       \
    {                                                                      \
        short4v ra, rb;                                                    \
        _Pragma("unroll")                                                  \
        for (int j = 0; j < 4; ++j) {                                      \
            ra[j] = (short)(va[j] & 0xffffu);                              \
            rb[j] = (short)(va[j] >> 16);                                  \
        }                                                                  \
        *(short4v*)&Vt[(off) + swz_v(vd0,     vkv0)] = ra;                 \
        *(short4v*)&Vt[(off) + swz_v(vd0 + 1, vkv0)] = rb;                 \
    }

    asm volatile("s_waitcnt vmcnt(0)" ::: "memory");
    ISSUE_V(0);
    ISSUE_K(0, 0);
    WRITE_V(0);
    int cur = 0;

    for (int it = 0; it < SEQ / 64; ++it) {
        const int nxt = cur ^ 1;
        const int ktn = (((it + 1) & (SEQ / 64 - 1))) * 64;
        ISSUE_V(ktn);
        ISSUE_K(ktn, nxt * KVB);
        asm volatile("s_waitcnt vmcnt(5)" ::: "memory");
        asm volatile("s_waitcnt lgkmcnt(0)" ::: "memory");
        __builtin_amdgcn_sched_barrier(0);
        __builtin_amdgcn_s_barrier();
        __builtin_amdgcn_sched_barrier(0);

        const int kO = cur * KVB;

        f32x4 st[4] = {};
        __builtin_amdgcn_s_setprio(1);
#pragma unroll
        for (int ks = 0; ks < 2; ++ks)
#pragma unroll
            for (int mf = 0; mf < 4; ++mf) {
                short8v kf = *(const short8v*)&Ks[kO + swz_u(mf * 16 + l15, ks * 32 + g * 8)];
                st[mf] = __builtin_amdgcn_mfma_f32_16x16x32_bf16(
                    kf, qf[ks], st[mf], 0, 0, 0);
            }
        __builtin_amdgcn_s_setprio(0);

        float vmax = st[0][0];
#pragma unroll
        for (int mf = 0; mf < 4; ++mf)
#pragma unroll
            for (int r = 0; r < 4; ++r)
                vmax = fmaxf(vmax, st[mf][r]);
        vmax = fmaxf(vmax, __shfl_xor(vmax, 16));
        vmax = fmaxf(vmax, __shfl_xor(vmax, 32));

        const bool grow = __any(vmax > mrun + 8.0f);
        if (grow) {
            float mnew = fmaxf(mrun, vmax);
            float corr = fexp2(mrun - mnew);
            mrun = mnew;
            if (g == 0) corrS[w][l15] = corr;
        }

#pragma unroll
        for (int mf = 0; mf < 4; ++mf)
#pragma unroll
            for (int r = 0; r < 4; ++r)
                st[mf][r] = fexp2(st[mf][r] - mrun);

        unsigned short* Pw = Ps[w];
#pragma unroll
        for (int mf = 0; mf < 4; ++mf) {
            uint2 pk;
            pk.x = cvt_pk_bf16(st[mf][0], st[mf][1]);
            pk.y = cvt_pk_bf16(st[mf][2], st[mf][3]);
            *(uint2*)&Pw[swz_u(l15, mf * 16 + g * 4)] = pk;
        }

        if (grow) {
            float4 cv = *(const float4*)&corrS[w][g * 4];
#pragma unroll
            for (int nd = 0; nd < 4; ++nd)
#pragma unroll
                for (int r = 0; r < 4; ++r)
                    o[nd][r] *= cv[r];
#pragma unroll
            for (int r = 0; r < 4; ++r) ol[r] *= cv[r];
        }

        __builtin_amdgcn_s_setprio(1);
#pragma unroll
        for (int ks2 = 0; ks2 < 2; ++ks2) {
            short8v pf = *(const short8v*)&Pw[swz_u(l15, ks2 * 32 + g * 8)];
            ol = __builtin_amdgcn_mfma_f32_16x16x32_bf16(
                pf, onesv, ol, 0, 0, 0);
#pragma unroll
            for (int nd = 0; nd < 4; ++nd) {
                short8v vf = *(const short8v*)&Vt[kO + swz_v(nd * 16 + l15, ks2 * 32 + g * 8)];
                o[nd] = __builtin_amdgcn_mfma_f32_16x16x32_bf16(
                    pf, vf, o[nd], 0, 0, 0);
            }
        }
        __builtin_amdgcn_s_setprio(0);

        WRITE_V(nxt * KVB);
        cur = nxt;
    }

#pragma unroll
    for (int r = 0; r < 4; ++r) {
        float inv = 1.f / (ol[r] + 1e-9f);
        long rowoff = headoff + (long)(q0w + g * 4 + r) * D_MODEL;
#pragma unroll
        for (int nd = 0; nd < 4; ++nd)
            Ob[rowoff + nd * 16 + l15] = f2bf(o[nd][r] * inv);
    }
#undef ISSUE_V
#undef ISSUE_K
#undef WRITE_V
}

// ---------------------------------------------------------------------------
// Launch
// ---------------------------------------------------------------------------
extern "C" void kernel_launch(void* const* d_in, const int* in_sizes, int n_in,
                              void* d_out, int out_size, void* d_ws, size_t ws_size,
                              hipStream_t stream) {
    // d_in order: 0 q, 1 k, 2 v, 3 Wq, 4 bq, 5 Wk, 6 bk, 7 Wv, 8 bv, 9 Wo, 10 bo
    unsigned short* ws  = (unsigned short*)d_ws;
    unsigned short* wb  = ws;                       // 4*WE  bf16 weights
    unsigned short* qkv = ws + 4L * WE;             // 3*XE  Q(scaled), K, V
    unsigned short* ob  = qkv + 3L * XE;            // XE    attention output

    ConvArgs ca;
    ca.src[0] = (const float*)d_in[3]; ca.dst[0] = wb;           ca.n4[0] = (int)(WE / 4);
    ca.src[1] = (const float*)d_in[5]; ca.dst[1] = wb + WE;      ca.n4[1] = (int)(WE / 4);
    ca.src[2] = (const float*)d_in[7]; ca.dst[2] = wb + 2L * WE; ca.n4[2] = (int)(WE / 4);
    ca.src[3] = (const float*)d_in[9]; ca.dst[3] = wb + 3L * WE; ca.n4[3] = (int)(WE / 4);

    hipLaunchKernelGGL(convert_kernel, dim3(512, 4), dim3(256), 0, stream, ca);

    hipLaunchKernelGGL(proj_kernel, dim3(768), dim3(256), 0, stream,
                       (const float*)d_in[0], (const float*)d_in[1],
                       (const float*)d_in[2], wb,
                       (const float*)d_in[4], (const float*)d_in[6],
                       (const float*)d_in[8], qkv);

    hipLaunchKernelGGL(attn_kernel, dim3(512), dim3(512), 0, stream,
                       qkv, qkv + XE, qkv + 2L * XE, ob);

    hipLaunchKernelGGL(out_kernel, dim3(256), dim3(256), 0, stream,
                       ob, wb + 3L * WE, (const float*)d_in[10], (float*)d_out);
}

// Round 38
// 122.521 us; speedup vs baseline: 1.0461x; 1.0069x over previous
//
#include <hip/hip_runtime.h>

// ---------------------------------------------------------------------------
// MultiHeadAttention forward, MI355X (gfx950).
// Weights-only fp32->bf16 convert; Q/K/V projections (128x128/BK=32,
// TRIPLE-buffered single-barrier, DEPTH-2 A-reg ping-pong prefetch, fused
// A-convert T14); flash attention v4b + XCD-chunked grid; output projection
// QUAD-buffered single-barrier with depth-2 prefetch (vmcnt(8)).
// ---------------------------------------------------------------------------

#define D_MODEL 1024
#define NHEADS  16
#define DKH     64
#define SEQ     2048
#define BATCH   2
#define MTOT    (BATCH * SEQ)            // 4096 rows
#define XE      ((long)MTOT * D_MODEL)   // 4194304 elems
#define WE      ((long)D_MODEL * D_MODEL)
#define QSCALE  0.18033688011112042f     // 0.125 * log2(e): softmax in exp2 domain

typedef __attribute__((ext_vector_type(8))) short short8v;   // 8 x bf16 (4 VGPR)
typedef __attribute__((ext_vector_type(4))) short short4v;   // 4 x bf16
typedef __attribute__((ext_vector_type(4))) float f32x4;     // MFMA C/D frag

typedef __attribute__((address_space(1))) void as1_void;
typedef __attribute__((address_space(3))) void as3_void;

__device__ __forceinline__ void gload16(const void* g, void* l) {
    __builtin_amdgcn_global_load_lds((const as1_void*)g, (as3_void*)l, 16, 0, 0);
}

__device__ __forceinline__ unsigned short f2bf(float x) {
    unsigned int u = __float_as_uint(x);
    u += 0x7FFFu + ((u >> 16) & 1u);     // RNE
    return (unsigned short)(u >> 16);
}

// native v_exp_f32: computes 2^x (avoid __exp2f: glibc name collision)
__device__ __forceinline__ float fexp2(float x) {
    return __builtin_amdgcn_exp2f(x);
}

// hardware packed f32x2 -> bf16x2 (RNE; one VALU op for two converts)
__device__ __forceinline__ unsigned int cvt_pk_bf16(float lo, float hi) {
    unsigned int r;
    asm("v_cvt_pk_bf16_f32 %0, %1, %2" : "=v"(r) : "v"(lo), "v"(hi));
    return r;
}

// XOR swizzle for [rows][64 bf16] LDS tiles (128B rows).
__device__ __forceinline__ int swz_u(int row, int col) {
    int byte = (col << 1) ^ ((row & 7) << 4);
    return (row << 6) + (byte >> 1);
}

// Vt swizzle: slot bits from (d&6)|((d>>3)&1): write pairs and reads stay 2-way.
__device__ __forceinline__ int swz_v(int d, int kv) {
    int slot = (d & 6) | ((d >> 3) & 1);
    int byte = (kv << 1) ^ (slot << 4);
    return (d << 6) + (byte >> 1);
}

// ---------------------------------------------------------------------------
// fp32 -> bf16 convert: WEIGHTS ONLY (Wq,Wk,Wv,Wo). blockIdx.y selects array.
// ---------------------------------------------------------------------------
struct ConvArgs {
    const float*    src[4];
    unsigned short* dst[4];
    int             n4[4];
};

__global__ __launch_bounds__(256) void convert_kernel(ConvArgs a) {
    int z = blockIdx.y;
    const float4*   s = (const float4*)a.src[z];
    unsigned short* d = a.dst[z];
    int n = a.n4[z];
    for (int i = blockIdx.x * blockDim.x + threadIdx.x; i < n;
         i += gridDim.x * blockDim.x) {
        float4 v = s[i];
        ushort4 o;
        o.x = f2bf(v.x); o.y = f2bf(v.y); o.z = f2bf(v.z); o.w = f2bf(v.w);
        *(ushort4*)(d + 4L * i) = o;
    }
}

// ---------------------------------------------------------------------------
// proj GEMM v8: 128x128 tile, BK=32, 4 waves, 256 threads, grid 768.
// TRIPLE-buffered (48 KB LDS, 3 blocks/CU), ONE barrier per iter, DEPTH-2
// A prefetch via X/Y reg ping-pong (loop unrolled x2 for static reg sets):
// iter i stages B(i+1) FIRST (order pinned by sched_barrier), then loads
// A(i+2) into the free reg set; barrier wait = vmcnt(10) (newer ops:
// A(i+1) 4 + B(i+1) 2 + A(i+2) 4), completing exactly B(i) which had one
// full iteration in flight. A regs are consumed 1.7 iters after issue.
// PWRITE at iter tail targets buf (i+1)%3 — disjoint from any reader
// (skew bound 1 iter => readers use buf i%3 or (i-1)%3).
// ---------------------------------------------------------------------------
__global__ __launch_bounds__(256) void proj_kernel(
    const float* __restrict__ xq, const float* __restrict__ xk,
    const float* __restrict__ xv, const unsigned short* __restrict__ wb,
    const float* __restrict__ bq, const float* __restrict__ bk,
    const float* __restrict__ bv, unsigned short* __restrict__ qkv) {
    __shared__ unsigned short As[3 * 128 * 32];   // 24 KB
    __shared__ unsigned short Bs[3 * 128 * 32];   // 24 KB

    const int t    = threadIdx.x;
    const int lane = t & 63;
    const int w    = t >> 6;
    const int wm   = w >> 1, wn = w & 1;
    const int l15  = lane & 15, g = lane >> 4;

    // XCD-chunked decode: 768 blocks; xcd owns M-tiles 4*xcd..4*xcd+3
    const int bid = blockIdx.x;
    const int xcd = bid & 7;
    const int k   = bid >> 3;            // 0..95 = 4(y) x 8(x) x 3(z)
    const int ty  = (xcd << 2) | (k & 3);
    const int tx  = (k >> 2) & 7;
    const int z   = k >> 5;
    const float* bias = (z == 0) ? bq : (z == 1) ? bk : bv;
    const float scale = (z == 0) ? QSCALE : 1.0f;

    const float* Af = (z == 0) ? xq : (z == 1) ? xk : xv;   // fp32 source
    const unsigned short* Bm = wb + (long)z * WE;
    unsigned short*       C  = qkv + (long)z * XE;
    const long m0 = (long)ty * 128;
    const long n0 = (long)tx * 128;
    const int  K  = D_MODEL;

    f32x4 acc[4][4] = {};

    // staging geometry: per matrix 512 16B-bf16-chunks; 2 per thread.
    const int idx0 = t, idx1 = t + 256;
    const int r0 = idx0 >> 2, c0 = (idx0 & 3) * 8;
    const int r1 = idx1 >> 2, c1 = (idx1 & 3) * 8;

    float4 ax0_[2], ax1_[2];   // reg set X (A tile in flight)
    float4 ay0_[2], ay1_[2];   // reg set Y

#define PLOAD(S0, S1, k0)                                                  \
    {                                                                      \
        const float* s0 = Af + (m0 + r0) * K + (k0) + c0;                  \
        const float* s1 = Af + (m0 + r1) * K + (k0) + c1;                  \
        S0[0] = *(const float4*)(s0);                                      \
        S1[0] = *(const float4*)(s0 + 4);                                  \
        S0[1] = *(const float4*)(s1);                                      \
        S1[1] = *(const float4*)(s1 + 4);                                  \
    }

#define PSTAGE_B(k0, buf)                                                  \
    gload16(Bm + (n0 + r0) * K + (k0) + c0, &Bs[(buf) * 4096 + idx0 * 8]); \
    gload16(Bm + (n0 + r1) * K + (k0) + c1, &Bs[(buf) * 4096 + idx1 * 8]);

#define PWRITE(S0, S1, buf)                                                \
    {                                                                      \
        uint4 pk;                                                          \
        pk.x = cvt_pk_bf16(S0[0].x, S0[0].y);                              \
        pk.y = cvt_pk_bf16(S0[0].z, S0[0].w);                              \
        pk.z = cvt_pk_bf16(S1[0].x, S1[0].y);                              \
        pk.w = cvt_pk_bf16(S1[0].z, S1[0].w);                              \
        *(uint4*)&As[(buf) * 4096 + idx0 * 8] = pk;                        \
        pk.x = cvt_pk_bf16(S0[1].x, S0[1].y);                              \
        pk.y = cvt_pk_bf16(S0[1].z, S0[1].w);                              \
        pk.z = cvt_pk_bf16(S1[1].x, S1[1].y);                              \
        pk.w = cvt_pk_bf16(S1[1].z, S1[1].w);                              \
        *(uint4*)&As[(buf) * 4096 + idx1 * 8] = pk;                        \
    }

#define PCOMPUTE(buf)                                                      \
    {                                                                      \
        const unsigned short* Ab = &As[(buf) * 4096];                      \
        const unsigned short* Bb = &Bs[(buf) * 4096];                      \
        short8v af[4], bf_[4];                                             \
        _Pragma("unroll")                                                  \
        for (int mf = 0; mf < 4; ++mf)                                     \
            af[mf] = *(const short8v*)&Ab[(wm * 64 + mf * 16 + l15) * 32 + g * 8]; \
        _Pragma("unroll")                                                  \
        for (int nf = 0; nf < 4; ++nf)                                     \
            bf_[nf] = *(const short8v*)&Bb[(wn * 64 + nf * 16 + l15) * 32 + g * 8]; \
        __builtin_amdgcn_s_setprio(1);                                     \
        _Pragma("unroll")                                                  \
        for (int mf = 0; mf < 4; ++mf)                                     \
            _Pragma("unroll")                                              \
            for (int nf = 0; nf < 4; ++nf)                                 \
                acc[mf][nf] = __builtin_amdgcn_mfma_f32_16x16x32_bf16(     \
                    af[mf], bf_[nf], acc[mf][nf], 0, 0, 0);                \
        __builtin_amdgcn_s_setprio(0);                                     \
    }

#define PBAR()                                                             \
    asm volatile("s_waitcnt vmcnt(10)" ::: "memory");                      \
    asm volatile("s_waitcnt lgkmcnt(0)" ::: "memory");                     \
    __builtin_amdgcn_sched_barrier(0);                                     \
    __builtin_amdgcn_s_barrier();                                          \
    __builtin_amdgcn_sched_barrier(0);

    // ---- prologue: tile0 -> buf0 (B staged, A via regs X); A tile1 -> Y ----
    PSTAGE_B(0, 0);
    PLOAD(ax0_, ax1_, 0);
    PWRITE(ax0_, ax1_, 0);        // one-time full-latency wait on X
    PLOAD(ay0_, ay1_, 32);        // A tile 1 in flight
    int cur = 0;

    for (int it = 0; it < K / 32; it += 2) {   // 32 iters, unrolled x2
        // ---- even iter: stage B(it+1), load A(it+2)->X, write A(it+1)<-Y ----
        {
            const int nxt = (cur == 2) ? 0 : cur + 1;
            PSTAGE_B(((it + 1) * 32) & (K - 1), nxt);
            __builtin_amdgcn_sched_barrier(0);   // pin B-before-A issue order
            PLOAD(ax0_, ax1_, ((it + 2) * 32) & (K - 1));
            PBAR();
            PCOMPUTE(cur);
            PWRITE(ay0_, ay1_, nxt);
            cur = nxt;
        }
        // ---- odd iter: stage B(it+2), load A(it+3)->Y, write A(it+2)<-X ----
        {
            const int nxt = (cur == 2) ? 0 : cur + 1;
            PSTAGE_B(((it + 2) * 32) & (K - 1), nxt);
            __builtin_amdgcn_sched_barrier(0);
            PLOAD(ay0_, ay1_, ((it + 3) * 32) & (K - 1));
            PBAR();
            PCOMPUTE(cur);
            PWRITE(ax0_, ax1_, nxt);
            cur = nxt;
        }
    }

    // ---- epilogue: bias + scale, bf16 write ----
    float bvv[4];
#pragma unroll
    for (int nf = 0; nf < 4; ++nf)
        bvv[nf] = bias[n0 + wn * 64 + nf * 16 + l15];

#pragma unroll
    for (int mf = 0; mf < 4; ++mf)
#pragma unroll
        for (int nf = 0; nf < 4; ++nf)
#pragma unroll
            for (int r = 0; r < 4; ++r) {
                long row = m0 + wm * 64 + mf * 16 + g * 4 + r;
                long col = n0 + wn * 64 + nf * 16 + l15;
                C[row * (long)D_MODEL + col] =
                    f2bf((acc[mf][nf][r] + bvv[nf]) * scale);
            }
#undef PLOAD
#undef PSTAGE_B
#undef PWRITE
#undef PCOMPUTE
#undef PBAR
}

// ---------------------------------------------------------------------------
// out GEMM v4: 128x128/BK=32, QUAD-buffered single-barrier, DEPTH-2 prefetch:
// iter i stages tile i+2 -> buf (i+2)&3, waits vmcnt(8) (tile i+1 4 +
// tile i+2 4 newer => completes tile i, staged 2 iters ago), computes
// buf i&3. Stager targets (i+2)&3 vs readers (i-1)&3 (diff 3) and i&3
// (diff 2) — disjoint under 1-iter skew. 64 KB LDS, 1 block/CU (grid 256).
// ---------------------------------------------------------------------------
__global__ __launch_bounds__(256) void out_kernel(
    const unsigned short* __restrict__ ob, const unsigned short* __restrict__ wo,
    const float* __restrict__ bo, float* __restrict__ out) {
    __shared__ unsigned short As[4 * 128 * 32];   // 32 KB
    __shared__ unsigned short Bs[4 * 128 * 32];   // 32 KB

    const int t    = threadIdx.x;
    const int lane = t & 63;
    const int w    = t >> 6;
    const int wm   = w >> 1, wn = w & 1;
    const int l15  = lane & 15, g = lane >> 4;

    const int bid = blockIdx.x;
    const int xcd = bid & 7;
    const int k   = bid >> 3;            // 0..31 = 4(y) x 8(x)
    const long m0 = (long)((xcd << 2) | (k & 3)) * 128;
    const long n0 = (long)(k >> 2) * 128;
    const int  K  = D_MODEL, N = D_MODEL;

    f32x4 acc[4][4] = {};

    const int idx0 = t, idx1 = t + 256;
    const int r0 = idx0 >> 2, c0 = (idx0 & 3) * 8;
    const int r1 = idx1 >> 2, c1 = (idx1 & 3) * 8;
    const unsigned short* pa0 = ob + (m0 + r0) * K + c0;
    const unsigned short* pa1 = ob + (m0 + r1) * K + c1;
    const unsigned short* pb0 = wo + (n0 + r0) * K + c0;
    const unsigned short* pb1 = wo + (n0 + r1) * K + c1;

#define OSTAGE(k0, buf)                                                    \
    gload16(pa0 + (k0), &As[(buf) * 4096 + idx0 * 8]);                     \
    gload16(pa1 + (k0), &As[(buf) * 4096 + idx1 * 8]);                     \
    gload16(pb0 + (k0), &Bs[(buf) * 4096 + idx0 * 8]);                     \
    gload16(pb1 + (k0), &Bs[(buf) * 4096 + idx1 * 8]);

    // ---- prologue: stage tiles 0,1 into buffers 0,1 ----
    OSTAGE(0, 0);
    OSTAGE(32, 1);
    int cur = 0;

    for (int it = 0; it < K / 32; ++it) {           // 32 iters, ONE barrier each
        const int nn = (cur + 2) & 3;
        const int kn = ((it + 2) * 32) & (K - 1);   // wrapped depth-2 prefetch
        OSTAGE(kn, nn);
        // outstanding: tile(i+1) 4 + tile(i+2) 4 = 8; completes tile i
        asm volatile("s_waitcnt vmcnt(8)" ::: "memory");
        __builtin_amdgcn_sched_barrier(0);
        __builtin_amdgcn_s_barrier();
        __builtin_amdgcn_sched_barrier(0);

        const unsigned short* Ab = &As[cur * 4096];
        const unsigned short* Bb = &Bs[cur * 4096];

        short8v af[4], bf_[4];
#pragma unroll
        for (int mf = 0; mf < 4; ++mf)
            af[mf] = *(const short8v*)&Ab[(wm * 64 + mf * 16 + l15) * 32 + g * 8];
#pragma unroll
        for (int nf = 0; nf < 4; ++nf)
            bf_[nf] = *(const short8v*)&Bb[(wn * 64 + nf * 16 + l15) * 32 + g * 8];
        __builtin_amdgcn_s_setprio(1);
#pragma unroll
        for (int mf = 0; mf < 4; ++mf)
#pragma unroll
            for (int nf = 0; nf < 4; ++nf)
                acc[mf][nf] = __builtin_amdgcn_mfma_f32_16x16x32_bf16(
                    af[mf], bf_[nf], acc[mf][nf], 0, 0, 0);
        __builtin_amdgcn_s_setprio(0);
        cur = (cur + 1) & 3;
    }

    float bvv[4];
#pragma unroll
    for (int nf = 0; nf < 4; ++nf)
        bvv[nf] = bo[n0 + wn * 64 + nf * 16 + l15];

#pragma unroll
    for (int mf = 0; mf < 4; ++mf)
#pragma unroll
        for (int nf = 0; nf < 4; ++nf)
#pragma unroll
            for (int r = 0; r < 4; ++r) {
                long row = m0 + wm * 64 + mf * 16 + g * 4 + r;
                long col = n0 + wn * 64 + nf * 16 + l15;
                out[row * (long)N + col] = acc[mf][nf][r] + bvv[nf];
            }
#undef OSTAGE
}

// ---------------------------------------------------------------------------
// Flash attention v4b + XCD-chunked grid (measured 63.0-63.8 us).
// ---------------------------------------------------------------------------
#define KVB 4096   // elems per K/V buffer (64 rows x 64)

__global__ __launch_bounds__(512) void attn_kernel(
    const unsigned short* __restrict__ Qb, const unsigned short* __restrict__ Kb,
    const unsigned short* __restrict__ Vb, unsigned short* __restrict__ Ob) {
    __shared__ alignas(16) unsigned short Ks[2 * KVB];     // 16 KB
    __shared__ alignas(16) unsigned short Vt[2 * KVB];     // 16 KB  V^T [d][kv]
    __shared__ alignas(16) unsigned short Ps[8][16 * 64];  // 16 KB  per-wave P
    __shared__ alignas(16) float corrS[8][16];

    const int t = threadIdx.x, lane = t & 63, w = t >> 6;
    const int l15 = lane & 15, g = lane >> 4;
    const int bid = blockIdx.x;
    const int xcd = bid & 7;
    const int kk2 = bid >> 3;              // 0..63
    const int bh  = (xcd << 2) | (kk2 & 3);
    const int qb  = kk2 >> 2;              // 0..15
    const long headoff = (long)(bh >> 4) * SEQ * D_MODEL + (long)(bh & 15) * DKH;
    const int q0w = qb * 128 + w * 16;

    short8v qf[2];
#pragma unroll
    for (int ks = 0; ks < 2; ++ks)
        qf[ks] = *(const short8v*)(Qb + headoff +
            (long)(q0w + l15) * D_MODEL + ks * 32 + g * 8);

    short8v onesv;
#pragma unroll
    for (int j = 0; j < 8; ++j) onesv[j] = (short)0x3F80;

    f32x4 o[4] = {};
    f32x4 ol = {};
    float mrun = -3.0e38f;

    const int vd0  = (t & 31) * 2;
    const int vkv0 = (t >> 5) * 4;
    const int kr0 = t >> 3, ks0 = t & 7;

    unsigned int va[4];

#define ISSUE_V(kt)                                                        \
    _Pragma("unroll")                                                      \
    for (int j = 0; j < 4; ++j)                                            \
        va[j] = *(const unsigned int*)(Vb + headoff +                      \
            (long)((kt) + vkv0 + j) * D_MODEL + vd0);

#define ISSUE_K(kt, off)                                                   \
    gload16(Kb + headoff + (long)((kt) + kr0) * D_MODEL +                  \
                ((ks0 ^ (kr0 & 7)) << 3), &Ks[(off) + t * 8]);

#define WRITE_V(off)                                                       \
    {                                                                      \
        short4v ra, rb;                                                    \
        _Pragma("unroll")                                                  \
        for (int j = 0; j < 4; ++j) {                                      \
            ra[j] = (short)(va[j] & 0xffffu);                              \
            rb[j] = (short)(va[j] >> 16);                                  \
        }                                                                  \
        *(short4v*)&Vt[(off) + swz_v(vd0,     vkv0)] = ra;                 \
        *(short4v*)&Vt[(off) + swz_v(vd0 + 1, vkv0)] = rb;                 \
    }

    asm volatile("s_waitcnt vmcnt(0)" ::: "memory");
    ISSUE_V(0);
    ISSUE_K(0, 0);
    WRITE_V(0);
    int cur = 0;

    for (int it = 0; it < SEQ / 64; ++it) {
        const int nxt = cur ^ 1;
        const int ktn = (((it + 1) & (SEQ / 64 - 1))) * 64;
        ISSUE_V(ktn);
        ISSUE_K(ktn, nxt * KVB);
        asm volatile("s_waitcnt vmcnt(5)" ::: "memory");
        asm volatile("s_waitcnt lgkmcnt(0)" ::: "memory");
        __builtin_amdgcn_sched_barrier(0);
        __builtin_amdgcn_s_barrier();
        __builtin_amdgcn_sched_barrier(0);

        const int kO = cur * KVB;

        f32x4 st[4] = {};
        __builtin_amdgcn_s_setprio(1);
#pragma unroll
        for (int ks = 0; ks < 2; ++ks)
#pragma unroll
            for (int mf = 0; mf < 4; ++mf) {
                short8v kf = *(const short8v*)&Ks[kO + swz_u(mf * 16 + l15, ks * 32 + g * 8)];
                st[mf] = __builtin_amdgcn_mfma_f32_16x16x32_bf16(
                    kf, qf[ks], st[mf], 0, 0, 0);
            }
        __builtin_amdgcn_s_setprio(0);

        float vmax = st[0][0];
#pragma unroll
        for (int mf = 0; mf < 4; ++mf)
#pragma unroll
            for (int r = 0; r < 4; ++r)
                vmax = fmaxf(vmax, st[mf][r]);
        vmax = fmaxf(vmax, __shfl_xor(vmax, 16));
        vmax = fmaxf(vmax, __shfl_xor(vmax, 32));

        const bool grow = __any(vmax > mrun + 8.0f);
        if (grow) {
            float mnew = fmaxf(mrun, vmax);
            float corr = fexp2(mrun - mnew);
            mrun = mnew;
            if (g == 0) corrS[w][l15] = corr;
        }

#pragma unroll
        for (int mf = 0; mf < 4; ++mf)
#pragma unroll
            for (int r = 0; r < 4; ++r)
                st[mf][r] = fexp2(st[mf][r] - mrun);

        unsigned short* Pw = Ps[w];
#pragma unroll
        for (int mf = 0; mf < 4; ++mf) {
            uint2 pk;
            pk.x = cvt_pk_bf16(st[mf][0], st[mf][1]);
            pk.y = cvt_pk_bf16(st[mf][2], st[mf][3]);
            *(uint2*)&Pw[swz_u(l15, mf * 16 + g * 4)] = pk;
        }

        if (grow) {
            float4 cv = *(const float4*)&corrS[w][g * 4];
#pragma unroll
            for (int nd = 0; nd < 4; ++nd)
#pragma unroll
                for (int r = 0; r < 4; ++r)
                    o[nd][r] *= cv[r];
#pragma unroll
            for (int r = 0; r < 4; ++r) ol[r] *= cv[r];
        }

        __builtin_amdgcn_s_setprio(1);
#pragma unroll
        for (int ks2 = 0; ks2 < 2; ++ks2) {
            short8v pf = *(const short8v*)&Pw[swz_u(l15, ks2 * 32 + g * 8)];
            ol = __builtin_amdgcn_mfma_f32_16x16x32_bf16(
                pf, onesv, ol, 0, 0, 0);
#pragma unroll
            for (int nd = 0; nd < 4; ++nd) {
                short8v vf = *(const short8v*)&Vt[kO + swz_v(nd * 16 + l15, ks2 * 32 + g * 8)];
                o[nd] = __builtin_amdgcn_mfma_f32_16x16x32_bf16(
                    pf, vf, o[nd], 0, 0, 0);
            }
        }
        __builtin_amdgcn_s_setprio(0);

        WRITE_V(nxt * KVB);
        cur = nxt;
    }

#pragma unroll
    for (int r = 0; r < 4; ++r) {
        float inv = 1.f / (ol[r] + 1e-9f);
        long rowoff = headoff + (long)(q0w + g * 4 + r) * D_MODEL;
#pragma unroll
        for (int nd = 0; nd < 4; ++nd)
            Ob[rowoff + nd * 16 + l15] = f2bf(o[nd][r] * inv);
    }
#undef ISSUE_V
#undef ISSUE_K
#undef WRITE_V
}

// ---------------------------------------------------------------------------
// Launch
// ---------------------------------------------------------------------------
extern "C" void kernel_launch(void* const* d_in, const int* in_sizes, int n_in,
                              void* d_out, int out_size, void* d_ws, size_t ws_size,
                              hipStream_t stream) {
    // d_in order: 0 q, 1 k, 2 v, 3 Wq, 4 bq, 5 Wk, 6 bk, 7 Wv, 8 bv, 9 Wo, 10 bo
    unsigned short* ws  = (unsigned short*)d_ws;
    unsigned short* wb  = ws;                       // 4*WE  bf16 weights
    unsigned short* qkv = ws + 4L * WE;             // 3*XE  Q(scaled), K, V
    unsigned short* ob  = qkv + 3L * XE;            // XE    attention output

    ConvArgs ca;
    ca.src[0] = (const float*)d_in[3]; ca.dst[0] = wb;           ca.n4[0] = (int)(WE / 4);
    ca.src[1] = (const float*)d_in[5]; ca.dst[1] = wb + WE;      ca.n4[1] = (int)(WE / 4);
    ca.src[2] = (const float*)d_in[7]; ca.dst[2] = wb + 2L * WE; ca.n4[2] = (int)(WE / 4);
    ca.src[3] = (const float*)d_in[9]; ca.dst[3] = wb + 3L * WE; ca.n4[3] = (int)(WE / 4);

    hipLaunchKernelGGL(convert_kernel, dim3(512, 4), dim3(256), 0, stream, ca);

    hipLaunchKernelGGL(proj_kernel, dim3(768), dim3(256), 0, stream,
                       (const float*)d_in[0], (const float*)d_in[1],
                       (const float*)d_in[2], wb,
                       (const float*)d_in[4], (const float*)d_in[6],
                       (const float*)d_in[8], qkv);

    hipLaunchKernelGGL(attn_kernel, dim3(512), dim3(512), 0, stream,
                       qkv, qkv + XE, qkv + 2L * XE, ob);

    hipLaunchKernelGGL(out_kernel, dim3(256), dim3(256), 0, stream,
                       ob, wb + 3L * WE, (const float*)d_in[10], (float*)d_out);
}